// Round 8
// baseline (144.747 us; speedup 1.0000x reference)
//
#include <hip/hip_runtime.h>
#include <hip/hip_bf16.h>
#include <cstdint>
#include <cstddef>

typedef __bf16 bf16;
typedef __bf16 bf16x8 __attribute__((ext_vector_type(8)));
typedef float f32x4 __attribute__((ext_vector_type(4)));

#define NB 2
#define SEQ 2048
#define DM 1024
#define MTOK 4096   // NB*SEQ
#define DL 256
#define NH 16
#define HD 64

#define LOG2E 1.4426950408889634f

__device__ __forceinline__ void gload16(const void* g, void* l) {
  __builtin_amdgcn_global_load_lds((const __attribute__((address_space(1))) void*)g,
                                   (__attribute__((address_space(3))) void*)l, 16, 0, 0);
}
__device__ __forceinline__ float fast_exp2(float x) {
#if __has_builtin(__builtin_amdgcn_exp2f)
  return __builtin_amdgcn_exp2f(x);
#else
  float r; asm("v_exp_f32 %0, %1" : "=v"(r) : "v"(x)); return r;
#endif
}
// bijective XCD swizzle (m204): XCD x = orig%8 gets a contiguous work range
__device__ __forceinline__ int xcd_swz(int orig, int nwg) {
  int x = orig & 7;
  int q = nwg >> 3, r = nwg & 7;
  int base = (x < r) ? x * (q + 1) : r * (q + 1) + (x - r) * q;
  return base + (orig >> 3);
}

// ================= fused prep kernel (memory-only) =================
__device__ __forceinline__ void transpose_dev(const float* __restrict__ in0,
                                              bf16* __restrict__ out, int R, int C,
                                              int c0, int r0, int tid, float (*tile)[33]) {
  int tx = tid & 31, ty = tid >> 5;  // 32 x 8 load shape
#pragma unroll
  for (int i = 0; i < 4; ++i) {
    int r = r0 + ty + 8 * i;
    tile[ty + 8 * i][tx] = in0[(size_t)r * C + c0 + tx];
  }
  __syncthreads();
  // write shape: thread (c=tid>>3, s=tid&7) stores 4 bf16 along out row c
  int c = tid >> 3, s = tid & 7;
  bf16 o4[4] __attribute__((aligned(8)));
#pragma unroll
  for (int j = 0; j < 4; ++j) o4[j] = (bf16)tile[4 * s + j][c];
  *reinterpret_cast<uint2*>(out + (size_t)(c0 + c) * R + r0 + 4 * s) =
      *reinterpret_cast<const uint2*>(o4);
}

__device__ __forceinline__ void cvt8_dev(const float* __restrict__ in, bf16* __restrict__ out,
                                         int blk, int tid) {
  int i = (blk * 256 + tid) * 8;
  float4 a = *reinterpret_cast<const float4*>(in + i);
  float4 b = *reinterpret_cast<const float4*>(in + i + 4);
  bf16 o[8] __attribute__((aligned(16)));
  o[0] = (bf16)a.x; o[1] = (bf16)a.y; o[2] = (bf16)a.z; o[3] = (bf16)a.w;
  o[4] = (bf16)b.x; o[5] = (bf16)b.y; o[6] = (bf16)b.z; o[7] = (bf16)b.w;
  *reinterpret_cast<uint4*>(out + i) = *reinterpret_cast<const uint4*>(o);
}

__device__ __forceinline__ void sum8_dev(const float* __restrict__ in0, const float* __restrict__ in1,
                                         bf16* __restrict__ out, int blk, int tid) {
  int i = (blk * 256 + tid) * 8;
  float4 a0 = *reinterpret_cast<const float4*>(in0 + i);
  float4 b0 = *reinterpret_cast<const float4*>(in0 + i + 4);
  float4 a1 = *reinterpret_cast<const float4*>(in1 + i);
  float4 b1 = *reinterpret_cast<const float4*>(in1 + i + 4);
  bf16 o[8] __attribute__((aligned(16)));
  o[0] = (bf16)(a0.x + a1.x); o[1] = (bf16)(a0.y + a1.y);
  o[2] = (bf16)(a0.z + a1.z); o[3] = (bf16)(a0.w + a1.w);
  o[4] = (bf16)(b0.x + b1.x); o[5] = (bf16)(b0.y + b1.y);
  o[6] = (bf16)(b0.z + b1.z); o[7] = (bf16)(b0.w + b1.w);
  *reinterpret_cast<uint4*>(out + i) = *reinterpret_cast<const uint4*>(o);
}

__global__ __launch_bounds__(256) void prep_kernel(const float* __restrict__ x,
                                                   const float* __restrict__ Wq,
                                                   const float* __restrict__ Wk,
                                                   const float* __restrict__ Wv,
                                                   const float* __restrict__ Wo,
                                                   const float* __restrict__ Wdn,
                                                   const float* __restrict__ Wuk,
                                                   const float* __restrict__ Wuv,
                                                   bf16* xbf, bf16* WqT, bf16* WoT, bf16* WdnT,
                                                   bf16* WukT, bf16* WuvT, bf16* Wkv) {
  __shared__ float tile[32][33];
  int id = blockIdx.x, tid = threadIdx.x;
  if (id < 2048) { cvt8_dev(x, xbf, id, tid); return; }
  id -= 2048;
  if (id < 512) { sum8_dev(Wk, Wv, Wkv, id, tid); return; }   // Wkv = bf16(Wk+Wv) row-major
  id -= 512;
  if (id < 1024) { transpose_dev(Wq, WqT, 1024, 1024, (id & 31) * 32, (id >> 5) * 32, tid, tile); return; }
  id -= 1024;
  if (id < 1024) { transpose_dev(Wo, WoT, 1024, 1024, (id & 31) * 32, (id >> 5) * 32, tid, tile); return; }
  id -= 1024;
  if (id < 256) { transpose_dev(Wdn, WdnT, 1024, 256, (id & 7) * 32, (id >> 3) * 32, tid, tile); return; }
  id -= 256;
  if (id < 256) { transpose_dev(Wuk, WukT, 256, 1024, (id & 31) * 32, (id >> 5) * 32, tid, tile); return; }
  id -= 256;
  transpose_dev(Wuv, WuvT, 256, 1024, (id & 31) * 32, (id >> 5) * 32, tid, tile);
}

// ================= 128xTN MFMA GEMM core, 2-phase dbuf =================
// EPI: 0 = bf16 row-major stride DM; 3 = f32 stride DM; 4 = up-proj split
//      (col<1024 -> kbuf bf16 stride DM, else vT transposed stride MTOK);
//      6 = bf16 + f32, stride DL
template <int TN, int EPI>
__device__ __forceinline__ void gemm_core(const bf16* __restrict__ A, const bf16* __restrict__ Bt,
                                          bf16* __restrict__ O1, bf16* __restrict__ O2,
                                          float* __restrict__ Of,
                                          int K, int bx, int by, bf16* As, bf16* Bs) {
  const int tid = threadIdx.x;
  const int lane = tid & 63;
  const int wv = tid >> 6;
  const int wr = wv >> 1, wc = wv & 1;
  const int row0 = bx * 128, col0 = by * TN;
  const int l15 = lane & 15;
  const int kq = (lane >> 4) * 8;
  constexpr int NR = TN / 32;          // col frags per wave
  constexpr int BSZ = TN * 32;

  const bf16* aS = A + (size_t)(row0 + (tid >> 2)) * K + (tid & 3) * 8;
  const bf16* bS = Bt + (size_t)(col0 + (tid >> 2)) * K + (tid & 3) * 8;
  const int d0 = tid * 8, d1 = tid * 8 + 2048;

  // prologue: stage k0=0 into buf 0
  gload16(aS, As + d0); gload16(aS + (size_t)64 * K, As + d1);
  gload16(bS, Bs + d0);
  if constexpr (TN == 128) gload16(bS + (size_t)64 * K, Bs + d1);
  aS += 32; bS += 32;

  f32x4 acc[4][NR] = {};
  int cur = 0;
  for (int k0 = 0; k0 < K; k0 += 32) {
    __syncthreads();
    if (k0 + 32 < K) {
      const int nxA = (cur ^ 1) * 4096, nxB = (cur ^ 1) * BSZ;
      gload16(aS, As + nxA + d0); gload16(aS + (size_t)64 * K, As + nxA + d1);
      gload16(bS, Bs + nxB + d0);
      if constexpr (TN == 128) gload16(bS + (size_t)64 * K, Bs + nxB + d1);
      aS += 32; bS += 32;
    }
    const bf16* Ab = As + cur * 4096;
    const bf16* Bb = Bs + cur * BSZ;
    bf16x8 af[4], bfr[NR];
#pragma unroll
    for (int m = 0; m < 4; ++m)
      af[m] = *reinterpret_cast<const bf16x8*>(&Ab[(wr * 64 + m * 16 + l15) * 32 + kq]);
#pragma unroll
    for (int n = 0; n < NR; ++n)
      bfr[n] = *reinterpret_cast<const bf16x8*>(&Bb[(wc * (TN / 2) + n * 16 + l15) * 32 + kq]);
    __builtin_amdgcn_s_setprio(1);
#pragma unroll
    for (int m = 0; m < 4; ++m)
#pragma unroll
      for (int n = 0; n < NR; ++n)
        acc[m][n] = __builtin_amdgcn_mfma_f32_16x16x32_bf16(af[m], bfr[n], acc[m][n], 0, 0, 0);
    __builtin_amdgcn_s_setprio(0);
    cur ^= 1;
  }

  const int rbase = row0 + wr * 64 + (lane >> 4) * 4;
  const int cbase = col0 + wc * (TN / 2) + l15;
#pragma unroll
  for (int m = 0; m < 4; ++m) {
#pragma unroll
    for (int n = 0; n < NR; ++n) {
      const int cc = cbase + n * 16;
      if constexpr (EPI == 0) {
#pragma unroll
        for (int r = 0; r < 4; ++r)
          O1[(size_t)(rbase + m * 16 + r) * DM + cc] = (bf16)acc[m][n][r];
      } else if constexpr (EPI == 3) {
#pragma unroll
        for (int r = 0; r < 4; ++r)
          Of[(size_t)(rbase + m * 16 + r) * DM + cc] = acc[m][n][r];
      } else if constexpr (EPI == 4) {
        if (cc < 1024) {
#pragma unroll
          for (int r = 0; r < 4; ++r)
            O1[(size_t)(rbase + m * 16 + r) * DM + cc] = (bf16)acc[m][n][r];
        } else {
          bf16 t4[4] __attribute__((aligned(8)));
#pragma unroll
          for (int r = 0; r < 4; ++r) t4[r] = (bf16)acc[m][n][r];
          *reinterpret_cast<uint2*>(O2 + (size_t)(cc - 1024) * MTOK + (rbase + m * 16)) =
              *reinterpret_cast<const uint2*>(t4);
        }
      } else {  // EPI == 6
#pragma unroll
        for (int r = 0; r < 4; ++r) {
          float v = acc[m][n][r];
          O1[(size_t)(rbase + m * 16 + r) * DL + cc] = (bf16)v;
          Of[(size_t)(rbase + m * 16 + r) * DL + cc] = v;
        }
      }
    }
  }
}

// q = x @ Wq (512) + WkvdT = Wdn^T @ (Wk+Wv)^T (32); XCD-swizzled
__global__ __launch_bounds__(256) void gemm_q_w(const bf16* __restrict__ xbf,
                                                const bf16* __restrict__ WqT, bf16* qbf,
                                                const bf16* __restrict__ WdnT,
                                                const bf16* __restrict__ Wkv, bf16* WkvdT) {
  __shared__ __align__(16) bf16 As[2 * 4096];
  __shared__ __align__(16) bf16 Bs[2 * 64 * 32];
  int id = xcd_swz(blockIdx.x, 544);
  if (id < 32)
    gemm_core<64, 0>(WdnT, Wkv, WkvdT, nullptr, nullptr, DM, id >> 4, id & 15, As, Bs);
  else {
    int j = id - 32;
    gemm_core<64, 0>(xbf, WqT, qbf, nullptr, nullptr, DM, j >> 4, j & 15, As, Bs);
  }
}

// latent = x @ Wkvd : N=256, TN=64 -> 128 blocks
__global__ __launch_bounds__(256) void gemm_latent(const bf16* __restrict__ xbf,
                                                   const bf16* __restrict__ WkvdT,
                                                   bf16* latbf, float* out_lat) {
  __shared__ __align__(16) bf16 As[2 * 4096];
  __shared__ __align__(16) bf16 Bs[2 * 64 * 32];
  int id = xcd_swz(blockIdx.x, 128);
  gemm_core<64, 6>(xbf, WkvdT, latbf, nullptr, out_lat, DM, id >> 2, id & 3, As, Bs);
}

// [k_rec | v^T] = latent @ [Wuk | Wuv] : N=2048, TN=64 -> 1024 blocks
__global__ __launch_bounds__(256) void gemm_up(const bf16* __restrict__ latbf,
                                               const bf16* __restrict__ WupT,
                                               bf16* kbuf, bf16* vT) {
  __shared__ __align__(16) bf16 As[2 * 4096];
  __shared__ __align__(16) bf16 Bs[2 * 64 * 32];
  int id = xcd_swz(blockIdx.x, 1024);
  gemm_core<64, 4>(latbf, WupT, kbuf, vT, nullptr, DL, id >> 5, id & 31, As, Bs);
}

// out0 = ctx @ Wo : N=1024, TN=64 -> 512 blocks
__global__ __launch_bounds__(256) void gemm_out(const bf16* __restrict__ ctx,
                                                const bf16* __restrict__ WoT, float* out0) {
  __shared__ __align__(16) bf16 As[2 * 4096];
  __shared__ __align__(16) bf16 Bs[2 * 64 * 32];
  int id = xcd_swz(blockIdx.x, 512);
  gemm_core<64, 3>(ctx, WoT, nullptr, nullptr, out0, DM, id >> 4, id & 15, As, Bs);
}

// ====== flash attention: KVBLK=128 (2x64 sub-tiles per barrier), no-max softmax ======
// per period: one barrier, stage next 128 keys, QK_A+QK_B, then {softmax_A,PV_A} and
// {softmax_B,PV_B} as independent chains so MFMA and VALU overlap within the wave.
__global__ __launch_bounds__(256) void attn_kernel(const bf16* __restrict__ Q,
                                                   const bf16* __restrict__ Kr,
                                                   const bf16* __restrict__ Vt,
                                                   bf16* __restrict__ Ctx) {
  __shared__ __align__(16) bf16 Ks[2 * 8192];   // [dbuf][half][64 keys x 64 d], swizzled
  __shared__ __align__(16) bf16 Vs[2 * 8192];   // [dbuf][half][64 d x 64 keys], swizzled
  __shared__ __align__(16) bf16 Ps[2 * 4096];   // [half][4 waves x 16 q x 64 keys]
  const int work = xcd_swz(blockIdx.x, SEQ / 64 * NH * NB);
  const int qt = work & 31, h = (work >> 5) & 15, b = work >> 9;
  const int tid = threadIdx.x, lane = tid & 63, wv = tid >> 6;
  const int l15 = lane & 15, lg = lane >> 4;
  const int qbase = qt * 64 + wv * 16;
  const size_t tok0 = (size_t)b * SEQ;

  bf16x8 qf[2];
  {
    const bf16* qp = Q + (tok0 + qbase + l15) * DM + h * HD + lg * 8;
    qf[0] = *reinterpret_cast<const bf16x8*>(qp);
    qf[1] = *reinterpret_cast<const bf16x8*>(qp + 32);
  }

  const int c1 = tid + 256;
  const int r0s = tid >> 3, r1s = c1 >> 3;
  const int cc0 = (tid & 7) ^ (r0s & 7), cc1 = (c1 & 7) ^ (r1s & 7);
  const bf16* kS0 = Kr + (tok0 + r0s) * DM + h * HD + cc0 * 8;
  const bf16* kS1 = Kr + (tok0 + r1s) * DM + h * HD + cc1 * 8;
  const bf16* vS0 = Vt + (size_t)(h * HD + r0s) * MTOK + tok0 + cc0 * 8;
  const bf16* vS1 = Vt + (size_t)(h * HD + r1s) * MTOK + tok0 + cc1 * 8;
  const int d0 = tid * 8, d1 = tid * 8 + 2048;

  // prologue: stage pair 0 (halves A,B) into buf 0
  gload16(kS0, Ks + d0); gload16(kS1, Ks + d1);
  gload16(kS0 + 64 * DM, Ks + 4096 + d0); gload16(kS1 + 64 * DM, Ks + 4096 + d1);
  gload16(vS0, Vs + d0); gload16(vS1, Vs + d1);
  gload16(vS0 + 64, Vs + 4096 + d0); gload16(vS1 + 64, Vs + 4096 + d1);
  kS0 += 128 * DM; kS1 += 128 * DM; vS0 += 128; vS1 += 128;

  int koff[2][4], poffw[4], poffr[2];
  const int hsw = l15 & 7;
#pragma unroll
  for (int ks = 0; ks < 2; ++ks)
#pragma unroll
    for (int nf = 0; nf < 4; ++nf) {
      int row = nf * 16 + l15;
      koff[ks][nf] = row * 64 + (((ks * 4 + lg) ^ (row & 7)) * 8);
    }
  const int psBase = wv * 1024 + l15 * 64;
#pragma unroll
  for (int nf = 0; nf < 4; ++nf)
    poffw[nf] = psBase + (((nf * 2 + (lg >> 1)) ^ hsw) * 8) + (lg & 1) * 4;
#pragma unroll
  for (int ks = 0; ks < 2; ++ks)
    poffr[ks] = psBase + (((ks * 4 + lg) ^ hsw) * 8);

  bf16x8 ones;
#pragma unroll
  for (int j = 0; j < 8; ++j) ones[j] = (bf16)1.0f;

  f32x4 oacc[4] = {};
  f32x4 lacc = {};
  float dec[4][4];
  const float DEC2C = (1.0f / 32.0f) * LOG2E;
  const float NC2 = -1.0e-4f * LOG2E;
  const float E64 = 0.99362048f, IE64 = 1.00642051f;
  const int ib = -qbase - l15 + lg * 4;

  // dec for tile 0 (key0 = 0)
#pragma unroll
  for (int nf = 0; nf < 4; ++nf)
#pragma unroll
    for (int r = 0; r < 4; ++r) {
      float df = (float)(ib + nf * 16 + r);
      dec[nf][r] = DEC2C * fast_exp2(NC2 * fabsf(df));
    }

  auto upd_dec = [&](int key0) {  // advance dec to the 64-key tile starting at key0
    bool before = (key0 + 63 < qbase);
    bool afterp = (key0 >= qbase + 79);
    if (!before && !afterp) {
#pragma unroll
      for (int nf = 0; nf < 4; ++nf)
#pragma unroll
        for (int r = 0; r < 4; ++r) {
          float df = (float)(key0 + ib + nf * 16 + r);
          dec[nf][r] = DEC2C * fast_exp2(NC2 * fabsf(df));
        }
    } else {
      float mlt = before ? IE64 : E64;
#pragma unroll
      for (int nf = 0; nf < 4; ++nf)
#pragma unroll
        for (int r = 0; r < 4; ++r) dec[nf][r] *= mlt;
    }
  };

  int cur = 0;
  for (int tp = 0; tp < 16; ++tp) {
    __syncthreads();   // buf[cur] (both halves) staged; prior reads drained
    if (tp + 1 < 16) {
      const int nx = (cur ^ 1) * 8192;
      gload16(kS0, Ks + nx + d0); gload16(kS1, Ks + nx + d1);
      gload16(kS0 + 64 * DM, Ks + nx + 4096 + d0); gload16(kS1 + 64 * DM, Ks + nx + 4096 + d1);
      gload16(vS0, Vs + nx + d0); gload16(vS1, Vs + nx + d1);
      gload16(vS0 + 64, Vs + nx + 4096 + d0); gload16(vS1 + 64, Vs + nx + 4096 + d1);
      kS0 += 128 * DM; kS1 += 128 * DM; vS0 += 128; vS1 += 128;
    }
    const int ka = cur * 8192;

    // ---- QK both halves (back-to-back MFMA)
    f32x4 scA[4] = {}, scB[4] = {};
    __builtin_amdgcn_s_setprio(1);
#pragma unroll
    for (int ks = 0; ks < 2; ++ks)
#pragma unroll
      for (int nf = 0; nf < 4; ++nf) {
        bf16x8 kf = *reinterpret_cast<const bf16x8*>(&Ks[ka + koff[ks][nf]]);
        scA[nf] = __builtin_amdgcn_mfma_f32_16x16x32_bf16(kf, qf[ks], scA[nf], 0, 0, 0);
      }
#pragma unroll
    for (int ks = 0; ks < 2; ++ks)
#pragma unroll
      for (int nf = 0; nf < 4; ++nf) {
        bf16x8 kf = *reinterpret_cast<const bf16x8*>(&Ks[ka + 4096 + koff[ks][nf]]);
        scB[nf] = __builtin_amdgcn_mfma_f32_16x16x32_bf16(kf, qf[ks], scB[nf], 0, 0, 0);
      }
    __builtin_amdgcn_s_setprio(0);

    // ---- softmax A -> Ps[0]
#pragma unroll
    for (int nf = 0; nf < 4; ++nf) {
      bf16 t4[4] __attribute__((aligned(8)));
#pragma unroll
      for (int r = 0; r < 4; ++r) t4[r] = (bf16)fast_exp2(scA[nf][r] * dec[nf][r]);
      *reinterpret_cast<uint2*>(&Ps[poffw[nf]]) = *reinterpret_cast<const uint2*>(t4);
    }
    bf16x8 pa[2];
    pa[0] = *reinterpret_cast<const bf16x8*>(&Ps[poffr[0]]);
    pa[1] = *reinterpret_cast<const bf16x8*>(&Ps[poffr[1]]);

    // ---- dec for half B (ready before PV_A so softmax_B can interleave)
    upd_dec(tp * 128 + 64);

    // ---- PV A + lsum
    __builtin_amdgcn_s_setprio(1);
#pragma unroll
    for (int ks = 0; ks < 2; ++ks) {
#pragma unroll
      for (int nf = 0; nf < 4; ++nf) {
        bf16x8 vf = *reinterpret_cast<const bf16x8*>(&Vs[ka + koff[ks][nf]]);
        oacc[nf] = __builtin_amdgcn_mfma_f32_16x16x32_bf16(vf, pa[ks], oacc[nf], 0, 0, 0);
      }
      lacc = __builtin_amdgcn_mfma_f32_16x16x32_bf16(ones, pa[ks], lacc, 0, 0, 0);
    }
    __builtin_amdgcn_s_setprio(0);

    // ---- softmax B -> Ps[1] (independent of PV_A; scheduler may overlap)
#pragma unroll
    for (int nf = 0; nf < 4; ++nf) {
      bf16 t4[4] __attribute__((aligned(8)));
#pragma unroll
      for (int r = 0; r < 4; ++r) t4[r] = (bf16)fast_exp2(scB[nf][r] * dec[nf][r]);
      *reinterpret_cast<uint2*>(&Ps[4096 + poffw[nf]]) = *reinterpret_cast<const uint2*>(t4);
    }
    bf16x8 pb[2];
    pb[0] = *reinterpret_cast<const bf16x8*>(&Ps[4096 + poffr[0]]);
    pb[1] = *reinterpret_cast<const bf16x8*>(&Ps[4096 + poffr[1]]);

    // ---- PV B + lsum
    __builtin_amdgcn_s_setprio(1);
#pragma unroll
    for (int ks = 0; ks < 2; ++ks) {
#pragma unroll
      for (int nf = 0; nf < 4; ++nf) {
        bf16x8 vf = *reinterpret_cast<const bf16x8*>(&Vs[ka + 4096 + koff[ks][nf]]);
        oacc[nf] = __builtin_amdgcn_mfma_f32_16x16x32_bf16(vf, pb[ks], oacc[nf], 0, 0, 0);
      }
      lacc = __builtin_amdgcn_mfma_f32_16x16x32_bf16(ones, pb[ks], lacc, 0, 0, 0);
    }
    __builtin_amdgcn_s_setprio(0);

    if (tp + 1 < 16) upd_dec((tp + 1) * 128);  // dec for next pair's half A
    cur ^= 1;
  }

  const float inv = 1.0f / lacc[0];
#pragma unroll
  for (int nf = 0; nf < 4; ++nf) {
    bf16 o4[4] __attribute__((aligned(8)));
#pragma unroll
    for (int r = 0; r < 4; ++r) o4[r] = (bf16)(oacc[nf][r] * inv);
    *reinterpret_cast<uint2*>(Ctx + (tok0 + qbase + l15) * DM + h * HD + nf * 16 + lg * 4) =
        *reinterpret_cast<const uint2*>(o4);
  }
}

// ================= launch =================
extern "C" void kernel_launch(void* const* d_in, const int* in_sizes, int n_in,
                              void* d_out, int out_size, void* d_ws, size_t ws_size,
                              hipStream_t stream) {
  const float* x   = (const float*)d_in[0];
  const float* Wq  = (const float*)d_in[1];
  const float* Wk  = (const float*)d_in[2];
  const float* Wv  = (const float*)d_in[3];
  const float* Wo  = (const float*)d_in[4];
  const float* Wdn = (const float*)d_in[5];
  const float* Wuk = (const float*)d_in[6];
  const float* Wuv = (const float*)d_in[7];
  float* out0 = (float*)d_out;                     // [4096][1024] f32
  float* out_lat = out0 + (size_t)MTOK * DM;       // [4096][256]  f32

  char* ws = (char*)d_ws;
  const size_t MB = 1u << 20;
  bf16* xbf   = (bf16*)(ws + 0);            // 8 MiB; reused as ctx
  bf16* qbf   = (bf16*)(ws + 8 * MB);       // 8 MiB
  bf16* kbuf  = (bf16*)(ws + 16 * MB);      // 8 MiB: k_rec (L4+); before that:
  bf16* Wkv   = kbuf;                       //   [16,18) Wkv bf16 [1024][1024] (dead after L2)
  bf16* WkvdT = (bf16*)(ws + 18 * MB);      //   [18,18.5) WkvdT [256][1024] (dead after L3)
  bf16* vT    = (bf16*)(ws + 24 * MB);      // 8 MiB: v_rec^T [1024][4096]
  bf16* latbf = (bf16*)(ws + 32 * MB);      // 2 MiB
  bf16* WqT   = (bf16*)(ws + 34 * MB);      // 2 MiB [1024][1024]
  bf16* WoT   = (bf16*)(ws + 36 * MB);      // 2 MiB
  bf16* WukT  = (bf16*)(ws + 38 * MB);      // 512 KiB [1024][256]
  bf16* WuvT  = (bf16*)(ws + 38 * MB + 512 * 1024);  // 512 KiB (contiguous -> WupT [2048][256])
  bf16* WdnT  = (bf16*)(ws + 39 * MB);      // 512 KiB [256][1024]
  bf16* ctx   = xbf;

  // L1: prep (memory-only)
  prep_kernel<<<5376, 256, 0, stream>>>(x, Wq, Wk, Wv, Wo, Wdn, Wuk, Wuv,
                                        xbf, WqT, WoT, WdnT, WukT, WuvT, Wkv);
  // L2: q = x@Wq (512) + WkvdT = Wdn^T@(Wk+Wv)^T (32)
  gemm_q_w<<<544, 256, 0, stream>>>(xbf, WqT, qbf, WdnT, Wkv, WkvdT);
  // L3: latent = x @ Wkvd
  gemm_latent<<<128, 256, 0, stream>>>(xbf, WkvdT, latbf, out_lat);
  // L4: [k_rec | v^T] = latent @ [Wuk | Wuv]
  gemm_up<<<1024, 256, 0, stream>>>(latbf, WukT, kbuf, vT);
  // L5: attention (KVBLK=128 paired sub-tiles + XCD swizzle)
  attn_kernel<<<1024, 256, 0, stream>>>(qbf, kbuf, vT, ctx);
  // L6: out0 = ctx @ Wo
  gemm_out<<<512, 256, 0, stream>>>(ctx, WoT, out0);

  (void)in_sizes; (void)n_in; (void)out_size; (void)ws_size;
}

// Round 9
// 134.852 us; speedup vs baseline: 1.0734x; 1.0734x over previous
//
#include <hip/hip_runtime.h>
#include <hip/hip_bf16.h>
#include <cstdint>
#include <cstddef>

typedef __bf16 bf16;
typedef __bf16 bf16x8 __attribute__((ext_vector_type(8)));
typedef float f32x4 __attribute__((ext_vector_type(4)));

#define NB 2
#define SEQ 2048
#define DM 1024
#define MTOK 4096   // NB*SEQ
#define DL 256
#define NH 16
#define HD 64

#define LOG2E 1.4426950408889634f

__device__ __forceinline__ void gload16(const void* g, void* l) {
  __builtin_amdgcn_global_load_lds((const __attribute__((address_space(1))) void*)g,
                                   (__attribute__((address_space(3))) void*)l, 16, 0, 0);
}
__device__ __forceinline__ float fast_exp2(float x) {
#if __has_builtin(__builtin_amdgcn_exp2f)
  return __builtin_amdgcn_exp2f(x);
#else
  float r; asm("v_exp_f32 %0, %1" : "=v"(r) : "v"(x)); return r;
#endif
}
// bijective XCD swizzle (m204): XCD x = orig%8 gets a contiguous work range
__device__ __forceinline__ int xcd_swz(int orig, int nwg) {
  int x = orig & 7;
  int q = nwg >> 3, r = nwg & 7;
  int base = (x < r) ? x * (q + 1) : r * (q + 1) + (x - r) * q;
  return base + (orig >> 3);
}

// ================= fused prep kernel (memory-only) =================
__device__ __forceinline__ void transpose_dev(const float* __restrict__ in0,
                                              bf16* __restrict__ out, int R, int C,
                                              int c0, int r0, int tid, float (*tile)[33]) {
  int tx = tid & 31, ty = tid >> 5;  // 32 x 8 load shape
#pragma unroll
  for (int i = 0; i < 4; ++i) {
    int r = r0 + ty + 8 * i;
    tile[ty + 8 * i][tx] = in0[(size_t)r * C + c0 + tx];
  }
  __syncthreads();
  // write shape: thread (c=tid>>3, s=tid&7) stores 4 bf16 along out row c
  int c = tid >> 3, s = tid & 7;
  bf16 o4[4] __attribute__((aligned(8)));
#pragma unroll
  for (int j = 0; j < 4; ++j) o4[j] = (bf16)tile[4 * s + j][c];
  *reinterpret_cast<uint2*>(out + (size_t)(c0 + c) * R + r0 + 4 * s) =
      *reinterpret_cast<const uint2*>(o4);
}

__device__ __forceinline__ void cvt8_dev(const float* __restrict__ in, bf16* __restrict__ out,
                                         int blk, int tid) {
  int i = (blk * 256 + tid) * 8;
  float4 a = *reinterpret_cast<const float4*>(in + i);
  float4 b = *reinterpret_cast<const float4*>(in + i + 4);
  bf16 o[8] __attribute__((aligned(16)));
  o[0] = (bf16)a.x; o[1] = (bf16)a.y; o[2] = (bf16)a.z; o[3] = (bf16)a.w;
  o[4] = (bf16)b.x; o[5] = (bf16)b.y; o[6] = (bf16)b.z; o[7] = (bf16)b.w;
  *reinterpret_cast<uint4*>(out + i) = *reinterpret_cast<const uint4*>(o);
}

__device__ __forceinline__ void sum8_dev(const float* __restrict__ in0, const float* __restrict__ in1,
                                         bf16* __restrict__ out, int blk, int tid) {
  int i = (blk * 256 + tid) * 8;
  float4 a0 = *reinterpret_cast<const float4*>(in0 + i);
  float4 b0 = *reinterpret_cast<const float4*>(in0 + i + 4);
  float4 a1 = *reinterpret_cast<const float4*>(in1 + i);
  float4 b1 = *reinterpret_cast<const float4*>(in1 + i + 4);
  bf16 o[8] __attribute__((aligned(16)));
  o[0] = (bf16)(a0.x + a1.x); o[1] = (bf16)(a0.y + a1.y);
  o[2] = (bf16)(a0.z + a1.z); o[3] = (bf16)(a0.w + a1.w);
  o[4] = (bf16)(b0.x + b1.x); o[5] = (bf16)(b0.y + b1.y);
  o[6] = (bf16)(b0.z + b1.z); o[7] = (bf16)(b0.w + b1.w);
  *reinterpret_cast<uint4*>(out + i) = *reinterpret_cast<const uint4*>(o);
}

__global__ __launch_bounds__(256) void prep_kernel(const float* __restrict__ x,
                                                   const float* __restrict__ Wq,
                                                   const float* __restrict__ Wk,
                                                   const float* __restrict__ Wv,
                                                   const float* __restrict__ Wo,
                                                   const float* __restrict__ Wdn,
                                                   const float* __restrict__ Wuk,
                                                   const float* __restrict__ Wuv,
                                                   bf16* xbf, bf16* WqT, bf16* WoT, bf16* WdnT,
                                                   bf16* WukT, bf16* WuvT, bf16* Wkv) {
  __shared__ float tile[32][33];
  int id = blockIdx.x, tid = threadIdx.x;
  if (id < 2048) { cvt8_dev(x, xbf, id, tid); return; }
  id -= 2048;
  if (id < 512) { sum8_dev(Wk, Wv, Wkv, id, tid); return; }   // Wkv = bf16(Wk+Wv) row-major
  id -= 512;
  if (id < 1024) { transpose_dev(Wq, WqT, 1024, 1024, (id & 31) * 32, (id >> 5) * 32, tid, tile); return; }
  id -= 1024;
  if (id < 1024) { transpose_dev(Wo, WoT, 1024, 1024, (id & 31) * 32, (id >> 5) * 32, tid, tile); return; }
  id -= 1024;
  if (id < 256) { transpose_dev(Wdn, WdnT, 1024, 256, (id & 7) * 32, (id >> 3) * 32, tid, tile); return; }
  id -= 256;
  if (id < 256) { transpose_dev(Wuk, WukT, 256, 1024, (id & 31) * 32, (id >> 5) * 32, tid, tile); return; }
  id -= 256;
  transpose_dev(Wuv, WuvT, 256, 1024, (id & 31) * 32, (id >> 5) * 32, tid, tile);
}

// ================= 128xTN MFMA GEMM core, 2-phase dbuf =================
// EPI: 0 = bf16 row-major stride DM; 3 = f32 stride DM; 6 = bf16 + f32, stride DL;
//      7 = bf16 row-major stride MTOK (vT = Wuv^T @ latent^T output [d][tok])
template <int TN, int EPI>
__device__ __forceinline__ void gemm_core(const bf16* __restrict__ A, const bf16* __restrict__ Bt,
                                          bf16* __restrict__ O1, bf16* __restrict__ O2,
                                          float* __restrict__ Of,
                                          int K, int bx, int by, bf16* As, bf16* Bs) {
  const int tid = threadIdx.x;
  const int lane = tid & 63;
  const int wv = tid >> 6;
  const int wr = wv >> 1, wc = wv & 1;
  const int row0 = bx * 128, col0 = by * TN;
  const int l15 = lane & 15;
  const int kq = (lane >> 4) * 8;
  constexpr int NR = TN / 32;          // col frags per wave
  constexpr int BSZ = TN * 32;

  const bf16* aS = A + (size_t)(row0 + (tid >> 2)) * K + (tid & 3) * 8;
  const bf16* bS = Bt + (size_t)(col0 + (tid >> 2)) * K + (tid & 3) * 8;
  const int d0 = tid * 8, d1 = tid * 8 + 2048;

  // prologue: stage k0=0 into buf 0
  gload16(aS, As + d0); gload16(aS + (size_t)64 * K, As + d1);
  gload16(bS, Bs + d0);
  if constexpr (TN == 128) gload16(bS + (size_t)64 * K, Bs + d1);
  aS += 32; bS += 32;

  f32x4 acc[4][NR] = {};
  int cur = 0;
  for (int k0 = 0; k0 < K; k0 += 32) {
    __syncthreads();
    if (k0 + 32 < K) {
      const int nxA = (cur ^ 1) * 4096, nxB = (cur ^ 1) * BSZ;
      gload16(aS, As + nxA + d0); gload16(aS + (size_t)64 * K, As + nxA + d1);
      gload16(bS, Bs + nxB + d0);
      if constexpr (TN == 128) gload16(bS + (size_t)64 * K, Bs + nxB + d1);
      aS += 32; bS += 32;
    }
    const bf16* Ab = As + cur * 4096;
    const bf16* Bb = Bs + cur * BSZ;
    bf16x8 af[4], bfr[NR];
#pragma unroll
    for (int m = 0; m < 4; ++m)
      af[m] = *reinterpret_cast<const bf16x8*>(&Ab[(wr * 64 + m * 16 + l15) * 32 + kq]);
#pragma unroll
    for (int n = 0; n < NR; ++n)
      bfr[n] = *reinterpret_cast<const bf16x8*>(&Bb[(wc * (TN / 2) + n * 16 + l15) * 32 + kq]);
    __builtin_amdgcn_s_setprio(1);
#pragma unroll
    for (int m = 0; m < 4; ++m)
#pragma unroll
      for (int n = 0; n < NR; ++n)
        acc[m][n] = __builtin_amdgcn_mfma_f32_16x16x32_bf16(af[m], bfr[n], acc[m][n], 0, 0, 0);
    __builtin_amdgcn_s_setprio(0);
    cur ^= 1;
  }

  const int rbase = row0 + wr * 64 + (lane >> 4) * 4;
  const int cbase = col0 + wc * (TN / 2) + l15;
#pragma unroll
  for (int m = 0; m < 4; ++m) {
#pragma unroll
    for (int n = 0; n < NR; ++n) {
      const int cc = cbase + n * 16;
      if constexpr (EPI == 0) {
#pragma unroll
        for (int r = 0; r < 4; ++r)
          O1[(size_t)(rbase + m * 16 + r) * DM + cc] = (bf16)acc[m][n][r];
      } else if constexpr (EPI == 3) {
#pragma unroll
        for (int r = 0; r < 4; ++r)
          Of[(size_t)(rbase + m * 16 + r) * DM + cc] = acc[m][n][r];
      } else if constexpr (EPI == 6) {
#pragma unroll
        for (int r = 0; r < 4; ++r) {
          float v = acc[m][n][r];
          O1[(size_t)(rbase + m * 16 + r) * DL + cc] = (bf16)v;
          Of[(size_t)(rbase + m * 16 + r) * DL + cc] = v;
        }
      } else {  // EPI == 7: [d][tok], stride MTOK
#pragma unroll
        for (int r = 0; r < 4; ++r)
          O1[(size_t)(rbase + m * 16 + r) * MTOK + cc] = (bf16)acc[m][n][r];
      }
    }
  }
}

// q = x @ Wq (512) + WkvdT = Wdn^T @ (Wk+Wv)^T (32); XCD-swizzled
__global__ __launch_bounds__(256) void gemm_q_w(const bf16* __restrict__ xbf,
                                                const bf16* __restrict__ WqT, bf16* qbf,
                                                const bf16* __restrict__ WdnT,
                                                const bf16* __restrict__ Wkv, bf16* WkvdT) {
  __shared__ __align__(16) bf16 As[2 * 4096];
  __shared__ __align__(16) bf16 Bs[2 * 64 * 32];
  int id = xcd_swz(blockIdx.x, 544);
  if (id < 32)
    gemm_core<64, 0>(WdnT, Wkv, WkvdT, nullptr, nullptr, DM, id >> 4, id & 15, As, Bs);
  else {
    int j = id - 32;
    gemm_core<64, 0>(xbf, WqT, qbf, nullptr, nullptr, DM, j >> 4, j & 15, As, Bs);
  }
}

// latent = x @ Wkvd : N=256, TN=64 -> 128 blocks
__global__ __launch_bounds__(256) void gemm_latent(const bf16* __restrict__ xbf,
                                                   const bf16* __restrict__ WkvdT,
                                                   bf16* latbf, float* out_lat) {
  __shared__ __align__(16) bf16 As[2 * 4096];
  __shared__ __align__(16) bf16 Bs[2 * 64 * 32];
  int id = xcd_swz(blockIdx.x, 128);
  gemm_core<64, 6>(xbf, WkvdT, latbf, nullptr, out_lat, DM, id >> 2, id & 3, As, Bs);
}

// L4: ids 0-511: k_rec = latent @ Wuk ([4096][1024], 32x16 tiles)
//     ids 512-1023: vT = Wuv^T @ latent^T ([1024 d][4096 tok], 8x64 tiles) -- operand swap
//     makes the vT write row-major (no 8B/8KB scatter)
__global__ __launch_bounds__(256) void gemm_up(const bf16* __restrict__ latbf,
                                               const bf16* __restrict__ WukT,
                                               const bf16* __restrict__ WuvT,
                                               bf16* kbuf, bf16* vT) {
  __shared__ __align__(16) bf16 As[2 * 4096];
  __shared__ __align__(16) bf16 Bs[2 * 64 * 32];
  int id = xcd_swz(blockIdx.x, 1024);
  if (id < 512)
    gemm_core<64, 0>(latbf, WukT, kbuf, nullptr, nullptr, DL, id >> 4, id & 15, As, Bs);
  else {
    int j = id - 512;
    gemm_core<64, 7>(WuvT, latbf, vT, nullptr, nullptr, DL, j >> 6, j & 63, As, Bs);
  }
}

// out0 = ctx @ Wo : N=1024, TN=64 -> 512 blocks
__global__ __launch_bounds__(256) void gemm_out(const bf16* __restrict__ ctx,
                                                const bf16* __restrict__ WoT, float* out0) {
  __shared__ __align__(16) bf16 As[2 * 4096];
  __shared__ __align__(16) bf16 Bs[2 * 64 * 32];
  int id = xcd_swz(blockIdx.x, 512);
  gemm_core<64, 3>(ctx, WoT, nullptr, nullptr, out0, DM, id >> 4, id & 15, As, Bs);
}

// ====== flash attention (round-7 proven): 2-phase dbuf, no-max softmax, MFMA row-sum ======
__global__ __launch_bounds__(256) void attn_kernel(const bf16* __restrict__ Q,
                                                   const bf16* __restrict__ Kr,
                                                   const bf16* __restrict__ Vt,
                                                   bf16* __restrict__ Ctx) {
  __shared__ __align__(16) bf16 Ks[2 * 4096];
  __shared__ __align__(16) bf16 Vs[2 * 4096];
  __shared__ __align__(16) bf16 Ps[4096];      // 4 waves x 16 q x 64 keys, XOR-swizzled
  const int work = xcd_swz(blockIdx.x, SEQ / 64 * NH * NB);
  const int qt = work & 31, h = (work >> 5) & 15, b = work >> 9;
  const int tid = threadIdx.x, lane = tid & 63, wv = tid >> 6;
  const int l15 = lane & 15, lg = lane >> 4;
  const int qbase = qt * 64 + wv * 16;
  const size_t tok0 = (size_t)b * SEQ;

  bf16x8 qf[2];
  {
    const bf16* qp = Q + (tok0 + qbase + l15) * DM + h * HD + lg * 8;
    qf[0] = *reinterpret_cast<const bf16x8*>(qp);
    qf[1] = *reinterpret_cast<const bf16x8*>(qp + 32);
  }

  const int c1 = tid + 256;
  const int r0s = tid >> 3, r1s = c1 >> 3;
  const int cc0 = (tid & 7) ^ (r0s & 7), cc1 = (c1 & 7) ^ (r1s & 7);
  const bf16* kS0 = Kr + (tok0 + r0s) * DM + h * HD + cc0 * 8;
  const bf16* kS1 = Kr + (tok0 + r1s) * DM + h * HD + cc1 * 8;
  const bf16* vS0 = Vt + (size_t)(h * HD + r0s) * MTOK + tok0 + cc0 * 8;
  const bf16* vS1 = Vt + (size_t)(h * HD + r1s) * MTOK + tok0 + cc1 * 8;
  const int d0 = tid * 8, d1 = tid * 8 + 2048;

  gload16(kS0, Ks + d0); gload16(kS1, Ks + d1);
  gload16(vS0, Vs + d0); gload16(vS1, Vs + d1);
  kS0 += 64 * DM; kS1 += 64 * DM; vS0 += 64; vS1 += 64;

  int koff[2][4], poffw[4], poffr[2];
  const int hsw = l15 & 7;
#pragma unroll
  for (int ks = 0; ks < 2; ++ks)
#pragma unroll
    for (int nf = 0; nf < 4; ++nf) {
      int row = nf * 16 + l15;
      koff[ks][nf] = row * 64 + (((ks * 4 + lg) ^ (row & 7)) * 8);
    }
  const int psBase = wv * 1024 + l15 * 64;
#pragma unroll
  for (int nf = 0; nf < 4; ++nf)
    poffw[nf] = psBase + (((nf * 2 + (lg >> 1)) ^ hsw) * 8) + (lg & 1) * 4;
#pragma unroll
  for (int ks = 0; ks < 2; ++ks)
    poffr[ks] = psBase + (((ks * 4 + lg) ^ hsw) * 8);

  bf16x8 ones;
#pragma unroll
  for (int j = 0; j < 8; ++j) ones[j] = (bf16)1.0f;

  f32x4 oacc[4] = {};
  f32x4 lacc = {};
  float dec[4][4];
  const float DEC2C = (1.0f / 32.0f) * LOG2E;
  const float NC2 = -1.0e-4f * LOG2E;
  const float E64 = 0.99362048f, IE64 = 1.00642051f;
  const int ib = -qbase - l15 + lg * 4;

  int cur = 0;
  for (int t = 0; t < SEQ / 64; ++t) {
    const int key0 = t * 64;
    __syncthreads();
    if (t + 1 < SEQ / 64) {
      const int nx = (cur ^ 1) * 4096;
      gload16(kS0, Ks + nx + d0); gload16(kS1, Ks + nx + d1);
      gload16(vS0, Vs + nx + d0); gload16(vS1, Vs + nx + d1);
      kS0 += 64 * DM; kS1 += 64 * DM; vS0 += 64; vS1 += 64;
    }
    {
      bool before = (key0 + 63 < qbase);
      bool afterp = (key0 >= qbase + 79);
      if (t == 0 || (!before && !afterp)) {
#pragma unroll
        for (int nf = 0; nf < 4; ++nf)
#pragma unroll
          for (int r = 0; r < 4; ++r) {
            float df = (float)(key0 + ib + nf * 16 + r);
            dec[nf][r] = DEC2C * fast_exp2(NC2 * fabsf(df));
          }
      } else {
        float mlt = before ? IE64 : E64;
#pragma unroll
        for (int nf = 0; nf < 4; ++nf)
#pragma unroll
          for (int r = 0; r < 4; ++r) dec[nf][r] *= mlt;
      }
    }
    const int kb = cur * 4096;

    // S^T[key][q] = K @ Q^T
    f32x4 sc[4] = {};
    __builtin_amdgcn_s_setprio(1);
#pragma unroll
    for (int ks = 0; ks < 2; ++ks)
#pragma unroll
      for (int nf = 0; nf < 4; ++nf) {
        bf16x8 kf = *reinterpret_cast<const bf16x8*>(&Ks[kb + koff[ks][nf]]);
        sc[nf] = __builtin_amdgcn_mfma_f32_16x16x32_bf16(kf, qf[ks], sc[nf], 0, 0, 0);
      }
    __builtin_amdgcn_s_setprio(0);

    // p = exp2(s * dec); pack to bf16, store to swizzled Ps
#pragma unroll
    for (int nf = 0; nf < 4; ++nf) {
      bf16 t4[4] __attribute__((aligned(8)));
#pragma unroll
      for (int r = 0; r < 4; ++r) t4[r] = (bf16)fast_exp2(sc[nf][r] * dec[nf][r]);
      *reinterpret_cast<uint2*>(&Ps[poffw[nf]]) = *reinterpret_cast<const uint2*>(t4);
    }
    bf16x8 pb[2];
    pb[0] = *reinterpret_cast<const bf16x8*>(&Ps[poffr[0]]);
    pb[1] = *reinterpret_cast<const bf16x8*>(&Ps[poffr[1]]);

    // O^T += V^T @ P^T ; row-sums via ones-MFMA
    __builtin_amdgcn_s_setprio(1);
#pragma unroll
    for (int ks = 0; ks < 2; ++ks) {
#pragma unroll
      for (int nf = 0; nf < 4; ++nf) {
        bf16x8 vf = *reinterpret_cast<const bf16x8*>(&Vs[kb + koff[ks][nf]]);
        oacc[nf] = __builtin_amdgcn_mfma_f32_16x16x32_bf16(vf, pb[ks], oacc[nf], 0, 0, 0);
      }
      lacc = __builtin_amdgcn_mfma_f32_16x16x32_bf16(ones, pb[ks], lacc, 0, 0, 0);
    }
    __builtin_amdgcn_s_setprio(0);
    cur ^= 1;
  }

  const float inv = 1.0f / lacc[0];
#pragma unroll
  for (int nf = 0; nf < 4; ++nf) {
    bf16 o4[4] __attribute__((aligned(8)));
#pragma unroll
    for (int r = 0; r < 4; ++r) o4[r] = (bf16)(oacc[nf][r] * inv);
    *reinterpret_cast<uint2*>(Ctx + (tok0 + qbase + l15) * DM + h * HD + nf * 16 + lg * 4) =
        *reinterpret_cast<const uint2*>(o4);
  }
}

// ================= launch =================
extern "C" void kernel_launch(void* const* d_in, const int* in_sizes, int n_in,
                              void* d_out, int out_size, void* d_ws, size_t ws_size,
                              hipStream_t stream) {
  const float* x   = (const float*)d_in[0];
  const float* Wq  = (const float*)d_in[1];
  const float* Wk  = (const float*)d_in[2];
  const float* Wv  = (const float*)d_in[3];
  const float* Wo  = (const float*)d_in[4];
  const float* Wdn = (const float*)d_in[5];
  const float* Wuk = (const float*)d_in[6];
  const float* Wuv = (const float*)d_in[7];
  float* out0 = (float*)d_out;                     // [4096][1024] f32
  float* out_lat = out0 + (size_t)MTOK * DM;       // [4096][256]  f32

  char* ws = (char*)d_ws;
  const size_t MB = 1u << 20;
  bf16* xbf   = (bf16*)(ws + 0);            // 8 MiB; reused as ctx
  bf16* qbf   = (bf16*)(ws + 8 * MB);       // 8 MiB
  bf16* kbuf  = (bf16*)(ws + 16 * MB);      // 8 MiB: k_rec (L4+); before that:
  bf16* Wkv   = kbuf;                       //   [16,18) Wkv bf16 [1024][1024] (dead after L2)
  bf16* WkvdT = (bf16*)(ws + 18 * MB);      //   [18,18.5) WkvdT [256][1024] (dead after L3)
  bf16* vT    = (bf16*)(ws + 24 * MB);      // 8 MiB: v_rec^T [1024][4096]
  bf16* latbf = (bf16*)(ws + 32 * MB);      // 2 MiB
  bf16* WqT   = (bf16*)(ws + 34 * MB);      // 2 MiB [1024][1024]
  bf16* WoT   = (bf16*)(ws + 36 * MB);      // 2 MiB
  bf16* WukT  = (bf16*)(ws + 38 * MB);      // 512 KiB [1024][256]
  bf16* WuvT  = (bf16*)(ws + 38 * MB + 512 * 1024);  // 512 KiB [1024][256]
  bf16* WdnT  = (bf16*)(ws + 39 * MB);      // 512 KiB [256][1024]
  bf16* ctx   = xbf;

  // L1: prep (memory-only)
  prep_kernel<<<5376, 256, 0, stream>>>(x, Wq, Wk, Wv, Wo, Wdn, Wuk, Wuv,
                                        xbf, WqT, WoT, WdnT, WukT, WuvT, Wkv);
  // L2: q = x@Wq (512) + WkvdT = Wdn^T@(Wk+Wv)^T (32)
  gemm_q_w<<<544, 256, 0, stream>>>(xbf, WqT, qbf, WdnT, Wkv, WkvdT);
  // L3: latent = x @ Wkvd
  gemm_latent<<<128, 256, 0, stream>>>(xbf, WkvdT, latbf, out_lat);
  // L4: k_rec = latent @ Wuk ; vT = Wuv^T @ latent^T (operand-swapped, coalesced writes)
  gemm_up<<<1024, 256, 0, stream>>>(latbf, WukT, WuvT, kbuf, vT);
  // L5: attention (round-7 proven structure + XCD swizzle)
  attn_kernel<<<1024, 256, 0, stream>>>(qbf, kbuf, vT, ctx);
  // L6: out0 = ctx @ Wo
  gemm_out<<<512, 256, 0, stream>>>(ctx, WoT, out0);

  (void)in_sizes; (void)n_in; (void)out_size; (void)ws_size;
}

// Round 10
// 123.187 us; speedup vs baseline: 1.1750x; 1.0947x over previous
//
#include <hip/hip_runtime.h>
#include <hip/hip_bf16.h>
#include <cstdint>
#include <cstddef>

typedef __bf16 bf16;
typedef __bf16 bf16x8 __attribute__((ext_vector_type(8)));
typedef float f32x4 __attribute__((ext_vector_type(4)));

#define NB 2
#define SEQ 2048
#define DM 1024
#define MTOK 4096   // NB*SEQ
#define DL 256
#define NH 16
#define HD 64

#define LOG2E 1.4426950408889634f

__device__ __forceinline__ void gload16(const void* g, void* l) {
  __builtin_amdgcn_global_load_lds((const __attribute__((address_space(1))) void*)g,
                                   (__attribute__((address_space(3))) void*)l, 16, 0, 0);
}
__device__ __forceinline__ float fast_exp2(float x) {
#if __has_builtin(__builtin_amdgcn_exp2f)
  return __builtin_amdgcn_exp2f(x);
#else
  float r; asm("v_exp_f32 %0, %1" : "=v"(r) : "v"(x)); return r;
#endif
}
// bijective XCD swizzle (m204): XCD x = orig%8 gets a contiguous work range
__device__ __forceinline__ int xcd_swz(int orig, int nwg) {
  int x = orig & 7;
  int q = nwg >> 3, r = nwg & 7;
  int base = (x < r) ? x * (q + 1) : r * (q + 1) + (x - r) * q;
  return base + (orig >> 3);
}

// ================= fused prep kernel (memory-only) =================
__device__ __forceinline__ void transpose_dev(const float* __restrict__ in0,
                                              bf16* __restrict__ out, int R, int C,
                                              int c0, int r0, int tid, float (*tile)[33]) {
  int tx = tid & 31, ty = tid >> 5;  // 32 x 8 load shape
#pragma unroll
  for (int i = 0; i < 4; ++i) {
    int r = r0 + ty + 8 * i;
    tile[ty + 8 * i][tx] = in0[(size_t)r * C + c0 + tx];
  }
  __syncthreads();
  // write shape: thread (c=tid>>3, s=tid&7) stores 4 bf16 along out row c
  int c = tid >> 3, s = tid & 7;
  bf16 o4[4] __attribute__((aligned(8)));
#pragma unroll
  for (int j = 0; j < 4; ++j) o4[j] = (bf16)tile[4 * s + j][c];
  *reinterpret_cast<uint2*>(out + (size_t)(c0 + c) * R + r0 + 4 * s) =
      *reinterpret_cast<const uint2*>(o4);
}

__device__ __forceinline__ void cvt8_dev(const float* __restrict__ in, bf16* __restrict__ out,
                                         int blk, int tid) {
  int i = (blk * 256 + tid) * 8;
  float4 a = *reinterpret_cast<const float4*>(in + i);
  float4 b = *reinterpret_cast<const float4*>(in + i + 4);
  bf16 o[8] __attribute__((aligned(16)));
  o[0] = (bf16)a.x; o[1] = (bf16)a.y; o[2] = (bf16)a.z; o[3] = (bf16)a.w;
  o[4] = (bf16)b.x; o[5] = (bf16)b.y; o[6] = (bf16)b.z; o[7] = (bf16)b.w;
  *reinterpret_cast<uint4*>(out + i) = *reinterpret_cast<const uint4*>(o);
}

__device__ __forceinline__ void sum8_dev(const float* __restrict__ in0, const float* __restrict__ in1,
                                         bf16* __restrict__ out, int blk, int tid) {
  int i = (blk * 256 + tid) * 8;
  float4 a0 = *reinterpret_cast<const float4*>(in0 + i);
  float4 b0 = *reinterpret_cast<const float4*>(in0 + i + 4);
  float4 a1 = *reinterpret_cast<const float4*>(in1 + i);
  float4 b1 = *reinterpret_cast<const float4*>(in1 + i + 4);
  bf16 o[8] __attribute__((aligned(16)));
  o[0] = (bf16)(a0.x + a1.x); o[1] = (bf16)(a0.y + a1.y);
  o[2] = (bf16)(a0.z + a1.z); o[3] = (bf16)(a0.w + a1.w);
  o[4] = (bf16)(b0.x + b1.x); o[5] = (bf16)(b0.y + b1.y);
  o[6] = (bf16)(b0.z + b1.z); o[7] = (bf16)(b0.w + b1.w);
  *reinterpret_cast<uint4*>(out + i) = *reinterpret_cast<const uint4*>(o);
}

__global__ __launch_bounds__(256) void prep_kernel(const float* __restrict__ x,
                                                   const float* __restrict__ Wq,
                                                   const float* __restrict__ Wk,
                                                   const float* __restrict__ Wv,
                                                   const float* __restrict__ Wo,
                                                   const float* __restrict__ Wdn,
                                                   const float* __restrict__ Wuk,
                                                   const float* __restrict__ Wuv,
                                                   bf16* xbf, bf16* WqT, bf16* WoT, bf16* WdnT,
                                                   bf16* WukT, bf16* WuvT, bf16* Wkv) {
  __shared__ float tile[32][33];
  int id = blockIdx.x, tid = threadIdx.x;
  if (id < 2048) { cvt8_dev(x, xbf, id, tid); return; }
  id -= 2048;
  if (id < 512) { sum8_dev(Wk, Wv, Wkv, id, tid); return; }   // Wkv = bf16(Wk+Wv) row-major
  id -= 512;
  if (id < 1024) { transpose_dev(Wq, WqT, 1024, 1024, (id & 31) * 32, (id >> 5) * 32, tid, tile); return; }
  id -= 1024;
  if (id < 1024) { transpose_dev(Wo, WoT, 1024, 1024, (id & 31) * 32, (id >> 5) * 32, tid, tile); return; }
  id -= 1024;
  if (id < 256) { transpose_dev(Wdn, WdnT, 1024, 256, (id & 7) * 32, (id >> 3) * 32, tid, tile); return; }
  id -= 256;
  if (id < 256) { transpose_dev(Wuk, WukT, 256, 1024, (id & 31) * 32, (id >> 5) * 32, tid, tile); return; }
  id -= 256;
  transpose_dev(Wuv, WuvT, 256, 1024, (id & 31) * 32, (id >> 5) * 32, tid, tile);
}

// ================= 128xTN MFMA GEMM core, 2-phase dbuf =================
// EPI: 0 = bf16 row-major stride DM; 3 = f32 stride DM;
//      7 = bf16 row-major stride MTOK (vT = Wuv^T @ latent^T output [d][tok])
template <int TN, int EPI>
__device__ __forceinline__ void gemm_core(const bf16* __restrict__ A, const bf16* __restrict__ Bt,
                                          bf16* __restrict__ O1, float* __restrict__ Of,
                                          int K, int bx, int by, bf16* As, bf16* Bs) {
  const int tid = threadIdx.x;
  const int lane = tid & 63;
  const int wv = tid >> 6;
  const int wr = wv >> 1, wc = wv & 1;
  const int row0 = bx * 128, col0 = by * TN;
  const int l15 = lane & 15;
  const int kq = (lane >> 4) * 8;
  constexpr int NR = TN / 32;          // col frags per wave
  constexpr int BSZ = TN * 32;

  const bf16* aS = A + (size_t)(row0 + (tid >> 2)) * K + (tid & 3) * 8;
  const bf16* bS = Bt + (size_t)(col0 + (tid >> 2)) * K + (tid & 3) * 8;
  const int d0 = tid * 8, d1 = tid * 8 + 2048;

  // prologue: stage k0=0 into buf 0
  gload16(aS, As + d0); gload16(aS + (size_t)64 * K, As + d1);
  gload16(bS, Bs + d0);
  if constexpr (TN == 128) gload16(bS + (size_t)64 * K, Bs + d1);
  aS += 32; bS += 32;

  f32x4 acc[4][NR] = {};
  int cur = 0;
  for (int k0 = 0; k0 < K; k0 += 32) {
    __syncthreads();
    if (k0 + 32 < K) {
      const int nxA = (cur ^ 1) * 4096, nxB = (cur ^ 1) * BSZ;
      gload16(aS, As + nxA + d0); gload16(aS + (size_t)64 * K, As + nxA + d1);
      gload16(bS, Bs + nxB + d0);
      if constexpr (TN == 128) gload16(bS + (size_t)64 * K, Bs + nxB + d1);
      aS += 32; bS += 32;
    }
    const bf16* Ab = As + cur * 4096;
    const bf16* Bb = Bs + cur * BSZ;
    bf16x8 af[4], bfr[NR];
#pragma unroll
    for (int m = 0; m < 4; ++m)
      af[m] = *reinterpret_cast<const bf16x8*>(&Ab[(wr * 64 + m * 16 + l15) * 32 + kq]);
#pragma unroll
    for (int n = 0; n < NR; ++n)
      bfr[n] = *reinterpret_cast<const bf16x8*>(&Bb[(wc * (TN / 2) + n * 16 + l15) * 32 + kq]);
    __builtin_amdgcn_s_setprio(1);
#pragma unroll
    for (int m = 0; m < 4; ++m)
#pragma unroll
      for (int n = 0; n < NR; ++n)
        acc[m][n] = __builtin_amdgcn_mfma_f32_16x16x32_bf16(af[m], bfr[n], acc[m][n], 0, 0, 0);
    __builtin_amdgcn_s_setprio(0);
    cur ^= 1;
  }

  const int rbase = row0 + wr * 64 + (lane >> 4) * 4;
  const int cbase = col0 + wc * (TN / 2) + l15;
#pragma unroll
  for (int m = 0; m < 4; ++m) {
#pragma unroll
    for (int n = 0; n < NR; ++n) {
      const int cc = cbase + n * 16;
      if constexpr (EPI == 0) {
#pragma unroll
        for (int r = 0; r < 4; ++r)
          O1[(size_t)(rbase + m * 16 + r) * DM + cc] = (bf16)acc[m][n][r];
      } else if constexpr (EPI == 3) {
#pragma unroll
        for (int r = 0; r < 4; ++r)
          Of[(size_t)(rbase + m * 16 + r) * DM + cc] = acc[m][n][r];
      } else {  // EPI == 7: [d][tok], stride MTOK
#pragma unroll
        for (int r = 0; r < 4; ++r)
          O1[(size_t)(rbase + m * 16 + r) * MTOK + cc] = (bf16)acc[m][n][r];
      }
    }
  }
}

// ================= 64x64 MFMA GEMM core (latent), 2-phase dbuf =================
__device__ __forceinline__ void gemm64_lat(const bf16* __restrict__ A, const bf16* __restrict__ Bt,
                                           bf16* __restrict__ O1, float* __restrict__ Of,
                                           int K, int bx, int by, bf16* As, bf16* Bs) {
  const int tid = threadIdx.x;
  const int lane = tid & 63;
  const int wv = tid >> 6;
  const int wr = wv >> 1, wc = wv & 1;
  const int row0 = bx * 64, col0 = by * 64;
  const int l15 = lane & 15;
  const int kq = (lane >> 4) * 8;

  const bf16* aS = A + (size_t)(row0 + (tid >> 2)) * K + (tid & 3) * 8;
  const bf16* bS = Bt + (size_t)(col0 + (tid >> 2)) * K + (tid & 3) * 8;
  const int d0 = tid * 8;

  gload16(aS, As + d0); gload16(bS, Bs + d0);
  aS += 32; bS += 32;

  f32x4 acc[2][2] = {};
  int cur = 0;
  for (int k0 = 0; k0 < K; k0 += 32) {
    __syncthreads();
    if (k0 + 32 < K) {
      const int nx = (cur ^ 1) * 2048;
      gload16(aS, As + nx + d0); gload16(bS, Bs + nx + d0);
      aS += 32; bS += 32;
    }
    const bf16* Ab = As + cur * 2048;
    const bf16* Bb = Bs + cur * 2048;
    bf16x8 af[2], bfr[2];
#pragma unroll
    for (int m = 0; m < 2; ++m)
      af[m] = *reinterpret_cast<const bf16x8*>(&Ab[(wr * 32 + m * 16 + l15) * 32 + kq]);
#pragma unroll
    for (int n = 0; n < 2; ++n)
      bfr[n] = *reinterpret_cast<const bf16x8*>(&Bb[(wc * 32 + n * 16 + l15) * 32 + kq]);
    __builtin_amdgcn_s_setprio(1);
#pragma unroll
    for (int m = 0; m < 2; ++m)
#pragma unroll
      for (int n = 0; n < 2; ++n)
        acc[m][n] = __builtin_amdgcn_mfma_f32_16x16x32_bf16(af[m], bfr[n], acc[m][n], 0, 0, 0);
    __builtin_amdgcn_s_setprio(0);
    cur ^= 1;
  }

  const int rbase = row0 + wr * 32 + (lane >> 4) * 4;
  const int cbase = col0 + wc * 32 + l15;
#pragma unroll
  for (int m = 0; m < 2; ++m)
#pragma unroll
    for (int n = 0; n < 2; ++n)
#pragma unroll
      for (int r = 0; r < 4; ++r) {
        float v = acc[m][n][r];
        O1[(size_t)(rbase + m * 16 + r) * DL + (cbase + n * 16)] = (bf16)v;
        Of[(size_t)(rbase + m * 16 + r) * DL + (cbase + n * 16)] = v;
      }
}

// q = x @ Wq (512) + WkvdT = Wdn^T @ (Wk+Wv)^T (32); XCD-swizzled
__global__ __launch_bounds__(256) void gemm_q_w(const bf16* __restrict__ xbf,
                                                const bf16* __restrict__ WqT, bf16* qbf,
                                                const bf16* __restrict__ WdnT,
                                                const bf16* __restrict__ Wkv, bf16* WkvdT) {
  __shared__ __align__(16) bf16 As[2 * 4096];
  __shared__ __align__(16) bf16 Bs[2 * 64 * 32];
  int id = xcd_swz(blockIdx.x, 544);
  if (id < 32)
    gemm_core<64, 0>(WdnT, Wkv, WkvdT, nullptr, DM, id >> 4, id & 15, As, Bs);
  else {
    int j = id - 32;
    gemm_core<64, 0>(xbf, WqT, qbf, nullptr, DM, j >> 4, j & 15, As, Bs);
  }
}

// latent = x @ Wkvd : 64x64 tiles -> 64x4 = 256 blocks (1/CU)
__global__ __launch_bounds__(256) void gemm_latent(const bf16* __restrict__ xbf,
                                                   const bf16* __restrict__ WkvdT,
                                                   bf16* latbf, float* out_lat) {
  __shared__ __align__(16) bf16 As[2 * 2048];
  __shared__ __align__(16) bf16 Bs[2 * 2048];
  int id = xcd_swz(blockIdx.x, 256);
  gemm64_lat(xbf, WkvdT, latbf, out_lat, DM, id >> 2, id & 3, As, Bs);
}

// L4: ids 0-511: k_rec = latent @ Wuk ; ids 512-1023: vT = Wuv^T @ latent^T
__global__ __launch_bounds__(256) void gemm_up(const bf16* __restrict__ latbf,
                                               const bf16* __restrict__ WukT,
                                               const bf16* __restrict__ WuvT,
                                               bf16* kbuf, bf16* vT) {
  __shared__ __align__(16) bf16 As[2 * 4096];
  __shared__ __align__(16) bf16 Bs[2 * 64 * 32];
  int id = xcd_swz(blockIdx.x, 1024);
  if (id < 512)
    gemm_core<64, 0>(latbf, WukT, kbuf, nullptr, DL, id >> 4, id & 15, As, Bs);
  else {
    int j = id - 512;
    gemm_core<64, 7>(WuvT, latbf, vT, nullptr, DL, j >> 6, j & 63, As, Bs);
  }
}

// out0 = ctx @ Wo : N=1024, TN=64 -> 512 blocks
__global__ __launch_bounds__(256) void gemm_out(const bf16* __restrict__ ctx,
                                                const bf16* __restrict__ WoT, float* out0) {
  __shared__ __align__(16) bf16 As[2 * 4096];
  __shared__ __align__(16) bf16 Bs[2 * 64 * 32];
  int id = xcd_swz(blockIdx.x, 512);
  gemm_core<64, 3>(ctx, WoT, nullptr, out0, DM, id >> 4, id & 15, As, Bs);
}

// ====== flash attention: 8 waves x 16 q = 128 q/block; same inner loop/sync as proven ======
// 512 blocks (2/CU, 16 waves/CU unchanged); staging per wave halved; K/V L2 reads halved
__global__ __launch_bounds__(512) void attn_kernel(const bf16* __restrict__ Q,
                                                   const bf16* __restrict__ Kr,
                                                   const bf16* __restrict__ Vt,
                                                   bf16* __restrict__ Ctx) {
  __shared__ __align__(16) bf16 Ks[2 * 4096];
  __shared__ __align__(16) bf16 Vs[2 * 4096];
  __shared__ __align__(16) bf16 Ps[8192];      // 8 waves x 16 q x 64 keys, XOR-swizzled
  const int work = xcd_swz(blockIdx.x, SEQ / 128 * NH * NB);   // 512
  const int qt = work & 15, h = (work >> 4) & 15, b = work >> 8;
  const int tid = threadIdx.x, lane = tid & 63, wv = tid >> 6;  // wv 0..7
  const int l15 = lane & 15, lg = lane >> 4;
  const int qbase = qt * 128 + wv * 16;
  const size_t tok0 = (size_t)b * SEQ;

  bf16x8 qf[2];
  {
    const bf16* qp = Q + (tok0 + qbase + l15) * DM + h * HD + lg * 8;
    qf[0] = *reinterpret_cast<const bf16x8*>(qp);
    qf[1] = *reinterpret_cast<const bf16x8*>(qp + 32);
  }

  // staging: 512 threads x 1 chunk per matrix; chunk tid: row=tid>>3, col-chunk (tid&7)^(row&7)
  const int r0s = tid >> 3;
  const int cc0 = (tid & 7) ^ (r0s & 7);
  const bf16* kS0 = Kr + (tok0 + r0s) * DM + h * HD + cc0 * 8;
  const bf16* vS0 = Vt + (size_t)(h * HD + r0s) * MTOK + tok0 + cc0 * 8;
  const int d0 = tid * 8;

  gload16(kS0, Ks + d0);
  gload16(vS0, Vs + d0);
  kS0 += 64 * DM; vS0 += 64;

  int koff[2][4], poffw[4], poffr[2];
  const int hsw = l15 & 7;
#pragma unroll
  for (int ks = 0; ks < 2; ++ks)
#pragma unroll
    for (int nf = 0; nf < 4; ++nf) {
      int row = nf * 16 + l15;
      koff[ks][nf] = row * 64 + (((ks * 4 + lg) ^ (row & 7)) * 8);
    }
  const int psBase = wv * 1024 + l15 * 64;
#pragma unroll
  for (int nf = 0; nf < 4; ++nf)
    poffw[nf] = psBase + (((nf * 2 + (lg >> 1)) ^ hsw) * 8) + (lg & 1) * 4;
#pragma unroll
  for (int ks = 0; ks < 2; ++ks)
    poffr[ks] = psBase + (((ks * 4 + lg) ^ hsw) * 8);

  bf16x8 ones;
#pragma unroll
  for (int j = 0; j < 8; ++j) ones[j] = (bf16)1.0f;

  f32x4 oacc[4] = {};
  f32x4 lacc = {};
  float dec[4][4];
  const float DEC2C = (1.0f / 32.0f) * LOG2E;
  const float NC2 = -1.0e-4f * LOG2E;
  const float E64 = 0.99362048f, IE64 = 1.00642051f;
  const int ib = -qbase - l15 + lg * 4;

  int cur = 0;
  for (int t = 0; t < SEQ / 64; ++t) {
    const int key0 = t * 64;
    __syncthreads();
    if (t + 1 < SEQ / 64) {
      const int nx = (cur ^ 1) * 4096;
      gload16(kS0, Ks + nx + d0);
      gload16(vS0, Vs + nx + d0);
      kS0 += 64 * DM; vS0 += 64;
    }
    {
      bool before = (key0 + 63 < qbase);
      bool afterp = (key0 >= qbase + 79);
      if (t == 0 || (!before && !afterp)) {
#pragma unroll
        for (int nf = 0; nf < 4; ++nf)
#pragma unroll
          for (int r = 0; r < 4; ++r) {
            float df = (float)(key0 + ib + nf * 16 + r);
            dec[nf][r] = DEC2C * fast_exp2(NC2 * fabsf(df));
          }
      } else {
        float mlt = before ? IE64 : E64;
#pragma unroll
        for (int nf = 0; nf < 4; ++nf)
#pragma unroll
          for (int r = 0; r < 4; ++r) dec[nf][r] *= mlt;
      }
    }
    const int kb = cur * 4096;

    // S^T[key][q] = K @ Q^T
    f32x4 sc[4] = {};
    __builtin_amdgcn_s_setprio(1);
#pragma unroll
    for (int ks = 0; ks < 2; ++ks)
#pragma unroll
      for (int nf = 0; nf < 4; ++nf) {
        bf16x8 kf = *reinterpret_cast<const bf16x8*>(&Ks[kb + koff[ks][nf]]);
        sc[nf] = __builtin_amdgcn_mfma_f32_16x16x32_bf16(kf, qf[ks], sc[nf], 0, 0, 0);
      }
    __builtin_amdgcn_s_setprio(0);

    // p = exp2(s * dec); pack to bf16, store to swizzled Ps
#pragma unroll
    for (int nf = 0; nf < 4; ++nf) {
      bf16 t4[4] __attribute__((aligned(8)));
#pragma unroll
      for (int r = 0; r < 4; ++r) t4[r] = (bf16)fast_exp2(sc[nf][r] * dec[nf][r]);
      *reinterpret_cast<uint2*>(&Ps[poffw[nf]]) = *reinterpret_cast<const uint2*>(t4);
    }
    bf16x8 pb[2];
    pb[0] = *reinterpret_cast<const bf16x8*>(&Ps[poffr[0]]);
    pb[1] = *reinterpret_cast<const bf16x8*>(&Ps[poffr[1]]);

    // O^T += V^T @ P^T ; row-sums via ones-MFMA
    __builtin_amdgcn_s_setprio(1);
#pragma unroll
    for (int ks = 0; ks < 2; ++ks) {
#pragma unroll
      for (int nf = 0; nf < 4; ++nf) {
        bf16x8 vf = *reinterpret_cast<const bf16x8*>(&Vs[kb + koff[ks][nf]]);
        oacc[nf] = __builtin_amdgcn_mfma_f32_16x16x32_bf16(vf, pb[ks], oacc[nf], 0, 0, 0);
      }
      lacc = __builtin_amdgcn_mfma_f32_16x16x32_bf16(ones, pb[ks], lacc, 0, 0, 0);
    }
    __builtin_amdgcn_s_setprio(0);
    cur ^= 1;
  }

  const float inv = 1.0f / lacc[0];
#pragma unroll
  for (int nf = 0; nf < 4; ++nf) {
    bf16 o4[4] __attribute__((aligned(8)));
#pragma unroll
    for (int r = 0; r < 4; ++r) o4[r] = (bf16)(oacc[nf][r] * inv);
    *reinterpret_cast<uint2*>(Ctx + (tok0 + qbase + l15) * DM + h * HD + nf * 16 + lg * 4) =
        *reinterpret_cast<const uint2*>(o4);
  }
}

// ================= launch =================
extern "C" void kernel_launch(void* const* d_in, const int* in_sizes, int n_in,
                              void* d_out, int out_size, void* d_ws, size_t ws_size,
                              hipStream_t stream) {
  const float* x   = (const float*)d_in[0];
  const float* Wq  = (const float*)d_in[1];
  const float* Wk  = (const float*)d_in[2];
  const float* Wv  = (const float*)d_in[3];
  const float* Wo  = (const float*)d_in[4];
  const float* Wdn = (const float*)d_in[5];
  const float* Wuk = (const float*)d_in[6];
  const float* Wuv = (const float*)d_in[7];
  float* out0 = (float*)d_out;                     // [4096][1024] f32
  float* out_lat = out0 + (size_t)MTOK * DM;       // [4096][256]  f32

  char* ws = (char*)d_ws;
  const size_t MB = 1u << 20;
  bf16* xbf   = (bf16*)(ws + 0);            // 8 MiB; reused as ctx
  bf16* qbf   = (bf16*)(ws + 8 * MB);       // 8 MiB
  bf16* kbuf  = (bf16*)(ws + 16 * MB);      // 8 MiB: k_rec (L4+); before that:
  bf16* Wkv   = kbuf;                       //   [16,18) Wkv bf16 [1024][1024] (dead after L2)
  bf16* WkvdT = (bf16*)(ws + 18 * MB);      //   [18,18.5) WkvdT [256][1024] (dead after L3)
  bf16* vT    = (bf16*)(ws + 24 * MB);      // 8 MiB: v_rec^T [1024][4096]
  bf16* latbf = (bf16*)(ws + 32 * MB);      // 2 MiB
  bf16* WqT   = (bf16*)(ws + 34 * MB);      // 2 MiB [1024][1024]
  bf16* WoT   = (bf16*)(ws + 36 * MB);      // 2 MiB
  bf16* WukT  = (bf16*)(ws + 38 * MB);      // 512 KiB [1024][256]
  bf16* WuvT  = (bf16*)(ws + 38 * MB + 512 * 1024);  // 512 KiB [1024][256]
  bf16* WdnT  = (bf16*)(ws + 39 * MB);      // 512 KiB [256][1024]
  bf16* ctx   = xbf;

  // L1: prep (memory-only)
  prep_kernel<<<5376, 256, 0, stream>>>(x, Wq, Wk, Wv, Wo, Wdn, Wuk, Wuv,
                                        xbf, WqT, WoT, WdnT, WukT, WuvT, Wkv);
  // L2: q = x@Wq (512) + WkvdT = Wdn^T@(Wk+Wv)^T (32)
  gemm_q_w<<<544, 256, 0, stream>>>(xbf, WqT, qbf, WdnT, Wkv, WkvdT);
  // L3: latent = x @ Wkvd (64x64 tiles, 256 blocks)
  gemm_latent<<<256, 256, 0, stream>>>(xbf, WkvdT, latbf, out_lat);
  // L4: k_rec = latent @ Wuk ; vT = Wuv^T @ latent^T
  gemm_up<<<1024, 256, 0, stream>>>(latbf, WukT, WuvT, kbuf, vT);
  // L5: attention (8 waves, 128 q/block, 512 blocks)
  attn_kernel<<<512, 512, 0, stream>>>(qbf, kbuf, vT, ctx);
  // L6: out0 = ctx @ Wo
  gemm_out<<<512, 256, 0, stream>>>(ctx, WoT, out0);

  (void)in_sizes; (void)n_in; (void)out_size; (void)ws_size;
}

// Round 11
// 115.448 us; speedup vs baseline: 1.2538x; 1.0670x over previous
//
#include <hip/hip_runtime.h>
#include <hip/hip_bf16.h>
#include <cstdint>
#include <cstddef>

typedef __bf16 bf16;
typedef __bf16 bf16x8 __attribute__((ext_vector_type(8)));
typedef float f32x4 __attribute__((ext_vector_type(4)));

#define NB 2
#define SEQ 2048
#define DM 1024
#define MTOK 4096   // NB*SEQ
#define DL 256
#define NH 16
#define HD 64

#define LOG2E 1.4426950408889634f

__device__ __forceinline__ void gload16(const void* g, void* l) {
  __builtin_amdgcn_global_load_lds((const __attribute__((address_space(1))) void*)g,
                                   (__attribute__((address_space(3))) void*)l, 16, 0, 0);
}
__device__ __forceinline__ float fast_exp2(float x) {
#if __has_builtin(__builtin_amdgcn_exp2f)
  return __builtin_amdgcn_exp2f(x);
#else
  float r; asm("v_exp_f32 %0, %1" : "=v"(r) : "v"(x)); return r;
#endif
}
// bijective XCD swizzle (m204): XCD x = orig%8 gets a contiguous work range
__device__ __forceinline__ int xcd_swz(int orig, int nwg) {
  int x = orig & 7;
  int q = nwg >> 3, r = nwg & 7;
  int base = (x < r) ? x * (q + 1) : r * (q + 1) + (x - r) * q;
  return base + (orig >> 3);
}

// ================= fused prep kernel (memory-only) =================
__device__ __forceinline__ void transpose_dev(const float* __restrict__ in0,
                                              bf16* __restrict__ out, int R, int C,
                                              int c0, int r0, int tid, float (*tile)[33]) {
  int tx = tid & 31, ty = tid >> 5;  // 32 x 8 load shape
#pragma unroll
  for (int i = 0; i < 4; ++i) {
    int r = r0 + ty + 8 * i;
    tile[ty + 8 * i][tx] = in0[(size_t)r * C + c0 + tx];
  }
  __syncthreads();
  // write shape: thread (c=tid>>3, s=tid&7) stores 4 bf16 along out row c
  int c = tid >> 3, s = tid & 7;
  bf16 o4[4] __attribute__((aligned(8)));
#pragma unroll
  for (int j = 0; j < 4; ++j) o4[j] = (bf16)tile[4 * s + j][c];
  *reinterpret_cast<uint2*>(out + (size_t)(c0 + c) * R + r0 + 4 * s) =
      *reinterpret_cast<const uint2*>(o4);
}

__device__ __forceinline__ void cvt8_dev(const float* __restrict__ in, bf16* __restrict__ out,
                                         int blk, int tid) {
  int i = (blk * 256 + tid) * 8;
  float4 a = *reinterpret_cast<const float4*>(in + i);
  float4 b = *reinterpret_cast<const float4*>(in + i + 4);
  bf16 o[8] __attribute__((aligned(16)));
  o[0] = (bf16)a.x; o[1] = (bf16)a.y; o[2] = (bf16)a.z; o[3] = (bf16)a.w;
  o[4] = (bf16)b.x; o[5] = (bf16)b.y; o[6] = (bf16)b.z; o[7] = (bf16)b.w;
  *reinterpret_cast<uint4*>(out + i) = *reinterpret_cast<const uint4*>(o);
}

__device__ __forceinline__ void sum8_dev(const float* __restrict__ in0, const float* __restrict__ in1,
                                         bf16* __restrict__ out, int blk, int tid) {
  int i = (blk * 256 + tid) * 8;
  float4 a0 = *reinterpret_cast<const float4*>(in0 + i);
  float4 b0 = *reinterpret_cast<const float4*>(in0 + i + 4);
  float4 a1 = *reinterpret_cast<const float4*>(in1 + i);
  float4 b1 = *reinterpret_cast<const float4*>(in1 + i + 4);
  bf16 o[8] __attribute__((aligned(16)));
  o[0] = (bf16)(a0.x + a1.x); o[1] = (bf16)(a0.y + a1.y);
  o[2] = (bf16)(a0.z + a1.z); o[3] = (bf16)(a0.w + a1.w);
  o[4] = (bf16)(b0.x + b1.x); o[5] = (bf16)(b0.y + b1.y);
  o[6] = (bf16)(b0.z + b1.z); o[7] = (bf16)(b0.w + b1.w);
  *reinterpret_cast<uint4*>(out + i) = *reinterpret_cast<const uint4*>(o);
}

__global__ __launch_bounds__(256) void prep_kernel(const float* __restrict__ x,
                                                   const float* __restrict__ Wq,
                                                   const float* __restrict__ Wk,
                                                   const float* __restrict__ Wv,
                                                   const float* __restrict__ Wo,
                                                   const float* __restrict__ Wdn,
                                                   const float* __restrict__ Wuk,
                                                   const float* __restrict__ Wuv,
                                                   bf16* xbf, bf16* WqT, bf16* WoT, bf16* WdnT,
                                                   bf16* WukT, bf16* WuvT, bf16* Wkv) {
  __shared__ float tile[32][33];
  int id = blockIdx.x, tid = threadIdx.x;
  if (id < 2048) { cvt8_dev(x, xbf, id, tid); return; }
  id -= 2048;
  if (id < 512) { sum8_dev(Wk, Wv, Wkv, id, tid); return; }   // Wkv = bf16(Wk+Wv) row-major
  id -= 512;
  if (id < 1024) { transpose_dev(Wq, WqT, 1024, 1024, (id & 31) * 32, (id >> 5) * 32, tid, tile); return; }
  id -= 1024;
  if (id < 1024) { transpose_dev(Wo, WoT, 1024, 1024, (id & 31) * 32, (id >> 5) * 32, tid, tile); return; }
  id -= 1024;
  if (id < 256) { transpose_dev(Wdn, WdnT, 1024, 256, (id & 7) * 32, (id >> 3) * 32, tid, tile); return; }
  id -= 256;
  if (id < 256) { transpose_dev(Wuk, WukT, 256, 1024, (id & 31) * 32, (id >> 5) * 32, tid, tile); return; }
  id -= 256;
  transpose_dev(Wuv, WuvT, 256, 1024, (id & 31) * 32, (id >> 5) * 32, tid, tile);
}

// ================= 128x64 MFMA GEMM core, BK=64, XOR-swizzled LDS, 2-phase dbuf =================
// Swizzle (rule #21): LDS chunk (row, p) holds global chunk p^(row&7); staged via pre-swizzled
// global source + linear gload16 dest; reads XOR the chunk index. 2-way banks (free).
// EPI: 0 = bf16 row-major stride DM; 3 = f32 stride DM; 7 = bf16 row-major stride MTOK
template <int EPI>
__device__ __forceinline__ void gemm_core(const bf16* __restrict__ A, const bf16* __restrict__ Bt,
                                          bf16* __restrict__ O1, float* __restrict__ Of,
                                          int K, int bx, int by, bf16* As, bf16* Bs) {
  const int tid = threadIdx.x;
  const int lane = tid & 63;
  const int wv = tid >> 6;
  const int wr = wv >> 1, wc = wv & 1;
  const int row0 = bx * 128, col0 = by * 64;
  const int l15 = lane & 15;
  const int lg = lane >> 4;

  // staging: A 128x64 = 1024 chunks (4/thread), B 64x64 = 512 chunks (2/thread)
  const int r0 = tid >> 3;
  const int ccs = (tid & 7) ^ (r0 & 7);          // pre-swizzled global chunk
  const bf16* aS = A + (size_t)(row0 + r0) * K + ccs * 8;
  const bf16* bS = Bt + (size_t)(col0 + r0) * K + ccs * 8;
  const int dA = tid * 8;

#pragma unroll
  for (int i = 0; i < 4; ++i) gload16(aS + (size_t)(32 * i) * K, As + dA + 2048 * i);
#pragma unroll
  for (int j = 0; j < 2; ++j) gload16(bS + (size_t)(32 * j) * K, Bs + dA + 2048 * j);
  aS += 64; bS += 64;

  // fragment read offsets (swizzled)
  int aoff[4][2], boff[2][2];
#pragma unroll
  for (int m = 0; m < 4; ++m) {
    int ra = wr * 64 + m * 16 + l15;
#pragma unroll
    for (int kk = 0; kk < 2; ++kk)
      aoff[m][kk] = ra * 64 + (((kk * 4 + lg) ^ (ra & 7)) * 8);
  }
#pragma unroll
  for (int n = 0; n < 2; ++n) {
    int rb = wc * 32 + n * 16 + l15;
#pragma unroll
    for (int kk = 0; kk < 2; ++kk)
      boff[n][kk] = rb * 64 + (((kk * 4 + lg) ^ (rb & 7)) * 8);
  }

  f32x4 acc[4][2] = {};
  int cur = 0;
  for (int k0 = 0; k0 < K; k0 += 64) {
    __syncthreads();
    if (k0 + 64 < K) {
      const int nxA = (cur ^ 1) * 8192, nxB = (cur ^ 1) * 4096;
#pragma unroll
      for (int i = 0; i < 4; ++i) gload16(aS + (size_t)(32 * i) * K, As + nxA + dA + 2048 * i);
#pragma unroll
      for (int j = 0; j < 2; ++j) gload16(bS + (size_t)(32 * j) * K, Bs + nxB + dA + 2048 * j);
      aS += 64; bS += 64;
    }
    const bf16* Ab = As + cur * 8192;
    const bf16* Bb = Bs + cur * 4096;
    bf16x8 af[4][2], bfr[2][2];
#pragma unroll
    for (int m = 0; m < 4; ++m)
#pragma unroll
      for (int kk = 0; kk < 2; ++kk)
        af[m][kk] = *reinterpret_cast<const bf16x8*>(&Ab[aoff[m][kk]]);
#pragma unroll
    for (int n = 0; n < 2; ++n)
#pragma unroll
      for (int kk = 0; kk < 2; ++kk)
        bfr[n][kk] = *reinterpret_cast<const bf16x8*>(&Bb[boff[n][kk]]);
    __builtin_amdgcn_s_setprio(1);
#pragma unroll
    for (int kk = 0; kk < 2; ++kk)
#pragma unroll
      for (int m = 0; m < 4; ++m)
#pragma unroll
        for (int n = 0; n < 2; ++n)
          acc[m][n] = __builtin_amdgcn_mfma_f32_16x16x32_bf16(af[m][kk], bfr[n][kk], acc[m][n], 0, 0, 0);
    __builtin_amdgcn_s_setprio(0);
    cur ^= 1;
  }

  const int rbase = row0 + wr * 64 + (lane >> 4) * 4;
  const int cbase = col0 + wc * 32 + l15;
#pragma unroll
  for (int m = 0; m < 4; ++m) {
#pragma unroll
    for (int n = 0; n < 2; ++n) {
      const int cc = cbase + n * 16;
      if constexpr (EPI == 0) {
#pragma unroll
        for (int r = 0; r < 4; ++r)
          O1[(size_t)(rbase + m * 16 + r) * DM + cc] = (bf16)acc[m][n][r];
      } else if constexpr (EPI == 3) {
#pragma unroll
        for (int r = 0; r < 4; ++r)
          Of[(size_t)(rbase + m * 16 + r) * DM + cc] = acc[m][n][r];
      } else {  // EPI == 7: [d][tok], stride MTOK
#pragma unroll
        for (int r = 0; r < 4; ++r)
          O1[(size_t)(rbase + m * 16 + r) * MTOK + cc] = (bf16)acc[m][n][r];
      }
    }
  }
}

// ================= 64x64 MFMA GEMM core (latent), BK=64, swizzled =================
__device__ __forceinline__ void gemm64_lat(const bf16* __restrict__ A, const bf16* __restrict__ Bt,
                                           bf16* __restrict__ O1, float* __restrict__ Of,
                                           int K, int bx, int by, bf16* As, bf16* Bs) {
  const int tid = threadIdx.x;
  const int lane = tid & 63;
  const int wv = tid >> 6;
  const int wr = wv >> 1, wc = wv & 1;
  const int row0 = bx * 64, col0 = by * 64;
  const int l15 = lane & 15;
  const int lg = lane >> 4;

  const int r0 = tid >> 3;
  const int ccs = (tid & 7) ^ (r0 & 7);
  const bf16* aS = A + (size_t)(row0 + r0) * K + ccs * 8;
  const bf16* bS = Bt + (size_t)(col0 + r0) * K + ccs * 8;
  const int dA = tid * 8;

#pragma unroll
  for (int j = 0; j < 2; ++j) {
    gload16(aS + (size_t)(32 * j) * K, As + dA + 2048 * j);
    gload16(bS + (size_t)(32 * j) * K, Bs + dA + 2048 * j);
  }
  aS += 64; bS += 64;

  int aoff[2][2], boff[2][2];
#pragma unroll
  for (int m = 0; m < 2; ++m) {
    int ra = wr * 32 + m * 16 + l15;
    int rb = wc * 32 + m * 16 + l15;
#pragma unroll
    for (int kk = 0; kk < 2; ++kk) {
      aoff[m][kk] = ra * 64 + (((kk * 4 + lg) ^ (ra & 7)) * 8);
      boff[m][kk] = rb * 64 + (((kk * 4 + lg) ^ (rb & 7)) * 8);
    }
  }

  f32x4 acc[2][2] = {};
  int cur = 0;
  for (int k0 = 0; k0 < K; k0 += 64) {
    __syncthreads();
    if (k0 + 64 < K) {
      const int nx = (cur ^ 1) * 4096;
#pragma unroll
      for (int j = 0; j < 2; ++j) {
        gload16(aS + (size_t)(32 * j) * K, As + nx + dA + 2048 * j);
        gload16(bS + (size_t)(32 * j) * K, Bs + nx + dA + 2048 * j);
      }
      aS += 64; bS += 64;
    }
    const bf16* Ab = As + cur * 4096;
    const bf16* Bb = Bs + cur * 4096;
    bf16x8 af[2][2], bfr[2][2];
#pragma unroll
    for (int m = 0; m < 2; ++m)
#pragma unroll
      for (int kk = 0; kk < 2; ++kk) {
        af[m][kk] = *reinterpret_cast<const bf16x8*>(&Ab[aoff[m][kk]]);
        bfr[m][kk] = *reinterpret_cast<const bf16x8*>(&Bb[boff[m][kk]]);
      }
    __builtin_amdgcn_s_setprio(1);
#pragma unroll
    for (int kk = 0; kk < 2; ++kk)
#pragma unroll
      for (int m = 0; m < 2; ++m)
#pragma unroll
        for (int n = 0; n < 2; ++n)
          acc[m][n] = __builtin_amdgcn_mfma_f32_16x16x32_bf16(af[m][kk], bfr[n][kk], acc[m][n], 0, 0, 0);
    __builtin_amdgcn_s_setprio(0);
    cur ^= 1;
  }

  const int rbase = row0 + wr * 32 + (lane >> 4) * 4;
  const int cbase = col0 + wc * 32 + l15;
#pragma unroll
  for (int m = 0; m < 2; ++m)
#pragma unroll
    for (int n = 0; n < 2; ++n)
#pragma unroll
      for (int r = 0; r < 4; ++r) {
        float v = acc[m][n][r];
        O1[(size_t)(rbase + m * 16 + r) * DL + (cbase + n * 16)] = (bf16)v;
        Of[(size_t)(rbase + m * 16 + r) * DL + (cbase + n * 16)] = v;
      }
}

// q = x @ Wq (512) + WkvdT = Wdn^T @ (Wk+Wv)^T (32); XCD-swizzled
__global__ __launch_bounds__(256) void gemm_q_w(const bf16* __restrict__ xbf,
                                                const bf16* __restrict__ WqT, bf16* qbf,
                                                const bf16* __restrict__ WdnT,
                                                const bf16* __restrict__ Wkv, bf16* WkvdT) {
  __shared__ __align__(16) bf16 As[2 * 8192];
  __shared__ __align__(16) bf16 Bs[2 * 4096];
  int id = xcd_swz(blockIdx.x, 544);
  if (id < 32)
    gemm_core<0>(WdnT, Wkv, WkvdT, nullptr, DM, id >> 4, id & 15, As, Bs);
  else {
    int j = id - 32;
    gemm_core<0>(xbf, WqT, qbf, nullptr, DM, j >> 4, j & 15, As, Bs);
  }
}

// latent = x @ Wkvd : 64x64 tiles -> 64x4 = 256 blocks (1/CU)
__global__ __launch_bounds__(256) void gemm_latent(const bf16* __restrict__ xbf,
                                                   const bf16* __restrict__ WkvdT,
                                                   bf16* latbf, float* out_lat) {
  __shared__ __align__(16) bf16 As[2 * 4096];
  __shared__ __align__(16) bf16 Bs[2 * 4096];
  int id = xcd_swz(blockIdx.x, 256);
  gemm64_lat(xbf, WkvdT, latbf, out_lat, DM, id >> 2, id & 3, As, Bs);
}

// L4: ids 0-511: k_rec = latent @ Wuk ; ids 512-1023: vT = Wuv^T @ latent^T
__global__ __launch_bounds__(256) void gemm_up(const bf16* __restrict__ latbf,
                                               const bf16* __restrict__ WukT,
                                               const bf16* __restrict__ WuvT,
                                               bf16* kbuf, bf16* vT) {
  __shared__ __align__(16) bf16 As[2 * 8192];
  __shared__ __align__(16) bf16 Bs[2 * 4096];
  int id = xcd_swz(blockIdx.x, 1024);
  if (id < 512)
    gemm_core<0>(latbf, WukT, kbuf, nullptr, DL, id >> 4, id & 15, As, Bs);
  else {
    int j = id - 512;
    gemm_core<7>(WuvT, latbf, vT, nullptr, DL, j >> 6, j & 63, As, Bs);
  }
}

// out0 = ctx @ Wo : N=1024 -> 512 blocks
__global__ __launch_bounds__(256) void gemm_out(const bf16* __restrict__ ctx,
                                                const bf16* __restrict__ WoT, float* out0) {
  __shared__ __align__(16) bf16 As[2 * 8192];
  __shared__ __align__(16) bf16 Bs[2 * 4096];
  int id = xcd_swz(blockIdx.x, 512);
  gemm_core<3>(ctx, WoT, nullptr, out0, DM, id >> 4, id & 15, As, Bs);
}

// ====== flash attention: 8 waves x 16 q = 128 q/block (round-10 proven) ======
__global__ __launch_bounds__(512) void attn_kernel(const bf16* __restrict__ Q,
                                                   const bf16* __restrict__ Kr,
                                                   const bf16* __restrict__ Vt,
                                                   bf16* __restrict__ Ctx) {
  __shared__ __align__(16) bf16 Ks[2 * 4096];
  __shared__ __align__(16) bf16 Vs[2 * 4096];
  __shared__ __align__(16) bf16 Ps[8192];      // 8 waves x 16 q x 64 keys, XOR-swizzled
  const int work = xcd_swz(blockIdx.x, SEQ / 128 * NH * NB);   // 512
  const int qt = work & 15, h = (work >> 4) & 15, b = work >> 8;
  const int tid = threadIdx.x, lane = tid & 63, wv = tid >> 6;  // wv 0..7
  const int l15 = lane & 15, lg = lane >> 4;
  const int qbase = qt * 128 + wv * 16;
  const size_t tok0 = (size_t)b * SEQ;

  bf16x8 qf[2];
  {
    const bf16* qp = Q + (tok0 + qbase + l15) * DM + h * HD + lg * 8;
    qf[0] = *reinterpret_cast<const bf16x8*>(qp);
    qf[1] = *reinterpret_cast<const bf16x8*>(qp + 32);
  }

  // staging: 512 threads x 1 chunk per matrix; chunk tid: row=tid>>3, col-chunk (tid&7)^(row&7)
  const int r0s = tid >> 3;
  const int cc0 = (tid & 7) ^ (r0s & 7);
  const bf16* kS0 = Kr + (tok0 + r0s) * DM + h * HD + cc0 * 8;
  const bf16* vS0 = Vt + (size_t)(h * HD + r0s) * MTOK + tok0 + cc0 * 8;
  const int d0 = tid * 8;

  gload16(kS0, Ks + d0);
  gload16(vS0, Vs + d0);
  kS0 += 64 * DM; vS0 += 64;

  int koff[2][4], poffw[4], poffr[2];
  const int hsw = l15 & 7;
#pragma unroll
  for (int ks = 0; ks < 2; ++ks)
#pragma unroll
    for (int nf = 0; nf < 4; ++nf) {
      int row = nf * 16 + l15;
      koff[ks][nf] = row * 64 + (((ks * 4 + lg) ^ (row & 7)) * 8);
    }
  const int psBase = wv * 1024 + l15 * 64;
#pragma unroll
  for (int nf = 0; nf < 4; ++nf)
    poffw[nf] = psBase + (((nf * 2 + (lg >> 1)) ^ hsw) * 8) + (lg & 1) * 4;
#pragma unroll
  for (int ks = 0; ks < 2; ++ks)
    poffr[ks] = psBase + (((ks * 4 + lg) ^ hsw) * 8);

  bf16x8 ones;
#pragma unroll
  for (int j = 0; j < 8; ++j) ones[j] = (bf16)1.0f;

  f32x4 oacc[4] = {};
  f32x4 lacc = {};
  float dec[4][4];
  const float DEC2C = (1.0f / 32.0f) * LOG2E;
  const float NC2 = -1.0e-4f * LOG2E;
  const float E64 = 0.99362048f, IE64 = 1.00642051f;
  const int ib = -qbase - l15 + lg * 4;

  int cur = 0;
  for (int t = 0; t < SEQ / 64; ++t) {
    const int key0 = t * 64;
    __syncthreads();
    if (t + 1 < SEQ / 64) {
      const int nx = (cur ^ 1) * 4096;
      gload16(kS0, Ks + nx + d0);
      gload16(vS0, Vs + nx + d0);
      kS0 += 64 * DM; vS0 += 64;
    }
    {
      bool before = (key0 + 63 < qbase);
      bool afterp = (key0 >= qbase + 79);
      if (t == 0 || (!before && !afterp)) {
#pragma unroll
        for (int nf = 0; nf < 4; ++nf)
#pragma unroll
          for (int r = 0; r < 4; ++r) {
            float df = (float)(key0 + ib + nf * 16 + r);
            dec[nf][r] = DEC2C * fast_exp2(NC2 * fabsf(df));
          }
      } else {
        float mlt = before ? IE64 : E64;
#pragma unroll
        for (int nf = 0; nf < 4; ++nf)
#pragma unroll
          for (int r = 0; r < 4; ++r) dec[nf][r] *= mlt;
      }
    }
    const int kb = cur * 4096;

    // S^T[key][q] = K @ Q^T
    f32x4 sc[4] = {};
    __builtin_amdgcn_s_setprio(1);
#pragma unroll
    for (int ks = 0; ks < 2; ++ks)
#pragma unroll
      for (int nf = 0; nf < 4; ++nf) {
        bf16x8 kf = *reinterpret_cast<const bf16x8*>(&Ks[kb + koff[ks][nf]]);
        sc[nf] = __builtin_amdgcn_mfma_f32_16x16x32_bf16(kf, qf[ks], sc[nf], 0, 0, 0);
      }
    __builtin_amdgcn_s_setprio(0);

    // p = exp2(s * dec); pack to bf16, store to swizzled Ps
#pragma unroll
    for (int nf = 0; nf < 4; ++nf) {
      bf16 t4[4] __attribute__((aligned(8)));
#pragma unroll
      for (int r = 0; r < 4; ++r) t4[r] = (bf16)fast_exp2(sc[nf][r] * dec[nf][r]);
      *reinterpret_cast<uint2*>(&Ps[poffw[nf]]) = *reinterpret_cast<const uint2*>(t4);
    }
    bf16x8 pb[2];
    pb[0] = *reinterpret_cast<const bf16x8*>(&Ps[poffr[0]]);
    pb[1] = *reinterpret_cast<const bf16x8*>(&Ps[poffr[1]]);

    // O^T += V^T @ P^T ; row-sums via ones-MFMA
    __builtin_amdgcn_s_setprio(1);
#pragma unroll
    for (int ks = 0; ks < 2; ++ks) {
#pragma unroll
      for (int nf = 0; nf < 4; ++nf) {
        bf16x8 vf = *reinterpret_cast<const bf16x8*>(&Vs[kb + koff[ks][nf]]);
        oacc[nf] = __builtin_amdgcn_mfma_f32_16x16x32_bf16(vf, pb[ks], oacc[nf], 0, 0, 0);
      }
      lacc = __builtin_amdgcn_mfma_f32_16x16x32_bf16(ones, pb[ks], lacc, 0, 0, 0);
    }
    __builtin_amdgcn_s_setprio(0);
    cur ^= 1;
  }

  const float inv = 1.0f / lacc[0];
#pragma unroll
  for (int nf = 0; nf < 4; ++nf) {
    bf16 o4[4] __attribute__((aligned(8)));
#pragma unroll
    for (int r = 0; r < 4; ++r) o4[r] = (bf16)(oacc[nf][r] * inv);
    *reinterpret_cast<uint2*>(Ctx + (tok0 + qbase + l15) * DM + h * HD + nf * 16 + lg * 4) =
        *reinterpret_cast<const uint2*>(o4);
  }
}

// ================= launch =================
extern "C" void kernel_launch(void* const* d_in, const int* in_sizes, int n_in,
                              void* d_out, int out_size, void* d_ws, size_t ws_size,
                              hipStream_t stream) {
  const float* x   = (const float*)d_in[0];
  const float* Wq  = (const float*)d_in[1];
  const float* Wk  = (const float*)d_in[2];
  const float* Wv  = (const float*)d_in[3];
  const float* Wo  = (const float*)d_in[4];
  const float* Wdn = (const float*)d_in[5];
  const float* Wuk = (const float*)d_in[6];
  const float* Wuv = (const float*)d_in[7];
  float* out0 = (float*)d_out;                     // [4096][1024] f32
  float* out_lat = out0 + (size_t)MTOK * DM;       // [4096][256]  f32

  char* ws = (char*)d_ws;
  const size_t MB = 1u << 20;
  bf16* xbf   = (bf16*)(ws + 0);            // 8 MiB; reused as ctx
  bf16* qbf   = (bf16*)(ws + 8 * MB);       // 8 MiB
  bf16* kbuf  = (bf16*)(ws + 16 * MB);      // 8 MiB: k_rec (L4+); before that:
  bf16* Wkv   = kbuf;                       //   [16,18) Wkv bf16 [1024][1024] (dead after L2)
  bf16* WkvdT = (bf16*)(ws + 18 * MB);      //   [18,18.5) WkvdT [256][1024] (dead after L3)
  bf16* vT    = (bf16*)(ws + 24 * MB);      // 8 MiB: v_rec^T [1024][4096]
  bf16* latbf = (bf16*)(ws + 32 * MB);      // 2 MiB
  bf16* WqT   = (bf16*)(ws + 34 * MB);      // 2 MiB [1024][1024]
  bf16* WoT   = (bf16*)(ws + 36 * MB);      // 2 MiB
  bf16* WukT  = (bf16*)(ws + 38 * MB);      // 512 KiB [1024][256]
  bf16* WuvT  = (bf16*)(ws + 38 * MB + 512 * 1024);  // 512 KiB [1024][256]
  bf16* WdnT  = (bf16*)(ws + 39 * MB);      // 512 KiB [256][1024]
  bf16* ctx   = xbf;

  // L1: prep (memory-only)
  prep_kernel<<<5376, 256, 0, stream>>>(x, Wq, Wk, Wv, Wo, Wdn, Wuk, Wuv,
                                        xbf, WqT, WoT, WdnT, WukT, WuvT, Wkv);
  // L2: q = x@Wq (512) + WkvdT = Wdn^T@(Wk+Wv)^T (32)
  gemm_q_w<<<544, 256, 0, stream>>>(xbf, WqT, qbf, WdnT, Wkv, WkvdT);
  // L3: latent = x @ Wkvd (64x64 tiles, 256 blocks)
  gemm_latent<<<256, 256, 0, stream>>>(xbf, WkvdT, latbf, out_lat);
  // L4: k_rec = latent @ Wuk ; vT = Wuv^T @ latent^T
  gemm_up<<<1024, 256, 0, stream>>>(latbf, WukT, WuvT, kbuf, vT);
  // L5: attention (8 waves, 128 q/block, 512 blocks)
  attn_kernel<<<512, 512, 0, stream>>>(qbf, kbuf, vT, ctx);
  // L6: out0 = ctx @ Wo
  gemm_out<<<512, 256, 0, stream>>>(ctx, WoT, out0);

  (void)in_sizes; (void)n_in; (void)out_size; (void)ws_size;
}